// Round 14
// baseline (1398.258 us; speedup 1.0000x reference)
//
#include <hip/hip_runtime.h>

typedef __bf16 bf16_t;
typedef __bf16 bf16x8 __attribute__((ext_vector_type(8)));
typedef float f32x4 __attribute__((ext_vector_type(4)));
typedef unsigned int u32;
typedef u32 u32x4 __attribute__((ext_vector_type(4)));

#define SEQ    1024
#define DEMB   1024
#define NHEAD  16
#define DVDIM  64
#define DMLP   4096
#define NVOCAB 32000
#define NLAYER 4

typedef const __attribute__((address_space(1))) void gas_t;
typedef __attribute__((address_space(3))) void las_t;

__device__ __forceinline__ void gload_lds16(const void* g, void* l) {
  __builtin_amdgcn_global_load_lds((gas_t*)g, (las_t*)l, 16, 0, 0);
}

union PackU { bf16_t h[2]; u32 u; };
union B4U  { uint2 u; bf16_t h[4]; };

// ---------------------------------------------------------------- reductions
__device__ __forceinline__ float blockSum(float v, float* red) {
  #pragma unroll
  for (int o = 32; o > 0; o >>= 1) v += __shfl_down(v, o, 64);
  __syncthreads();
  if ((threadIdx.x & 63) == 0) red[threadIdx.x >> 6] = v;
  __syncthreads();
  return (red[0] + red[1]) + (red[2] + red[3]);
}

// ---------------------------------------------------------------- LN body
__device__ __forceinline__ void ln_body(float4 v, const float* __restrict__ g,
                                        const float* __restrict__ b,
                                        bf16_t* __restrict__ xn, int row, int t,
                                        float* red, float* xupd_row) {
  float mu = blockSum(v.x + v.y + v.z + v.w, red) * (1.0f / DEMB);
  float dx = v.x - mu, dy = v.y - mu, dz = v.z - mu, dw = v.w - mu;
  float var = blockSum(dx * dx + dy * dy + dz * dz + dw * dw, red) * (1.0f / DEMB);
  float inv = 1.0f / sqrtf(var);
  float4 gv = *(const float4*)(g + t * 4);
  float4 bv = *(const float4*)(b + t * 4);
  float o0 = gv.x * dx * inv + bv.x;
  float o1 = gv.y * dy * inv + bv.y;
  float o2 = gv.z * dz * inv + bv.z;
  float o3 = gv.w * dw * inv + bv.w;
  PackU p0, p1;
  p0.h[0] = (bf16_t)o0; p0.h[1] = (bf16_t)o1;
  p1.h[0] = (bf16_t)o2; p1.h[1] = (bf16_t)o3;
  uint2 st; st.x = p0.u; st.y = p1.u;
  *(uint2*)(xn + (long)row * DEMB + t * 4) = st;
  if (xupd_row) {
    float4 nv; nv.x = v.x + o0; nv.y = v.y + o1; nv.z = v.z + o2; nv.w = v.w + o3;
    *(float4*)(xupd_row + t * 4) = nv;
  }
}

// ---------------------------------------------------------------- prologue combo: embed+LN1(l0) | bias concat | Yb zero
__global__ void __launch_bounds__(256)
embedlnbias_k(const int* __restrict__ ids, const float* __restrict__ we,
              const float* __restrict__ pe, const float* __restrict__ g,
              const float* __restrict__ b, float* __restrict__ x,
              bf16_t* __restrict__ xn,
              const float* __restrict__ bq, const float* __restrict__ bk,
              float* __restrict__ bias_out, bf16_t* __restrict__ y) {
  __shared__ float red[4];
  const int bidx = blockIdx.x, t = threadIdx.x;
  if (bidx < SEQ) {
    const int row = bidx;
    const long id = ids[row];
    float4 a = *(const float4*)(we + id * (long)DEMB + t * 4);
    float4 p = *(const float4*)(pe + (long)row * DEMB + t * 4);
    float4 v; v.x = a.x + p.x; v.y = a.y + p.y; v.z = a.z + p.z; v.w = a.w + p.w;
    *(float4*)(x + (long)row * DEMB + t * 4) = v;
    ln_body(v, g, b, xn, row, t, red, nullptr);
  } else if (bidx < SEQ + 128) {
    const int z = bidx - SEQ;
    const int l = z >> 5, i = z & 31;
    const float* src = (i < NHEAD) ? (bq + (long)(l * NHEAD + i) * DEMB)
                                   : (bk + (long)(l * NHEAD + i - NHEAD) * DEMB);
    *(float4*)(bias_out + (long)z * DEMB + t * 4) = *(const float4*)(src + t * 4);
  } else {
    const int z = bidx - SEQ - 128;
    *(uint4*)((char*)y + ((long)z * 256 + t) * 16) = uint4{0, 0, 0, 0};
  }
}

// ---------------------------------------------------------------- layernorm (mid-layer ln2)
__global__ void __launch_bounds__(256)
ln_k(const float* __restrict__ x, const float* __restrict__ g,
     const float* __restrict__ b, bf16_t* __restrict__ xn,
     float* __restrict__ xupd) {
  __shared__ float red[4];
  const int row = blockIdx.x, t = threadIdx.x;
  float4 v = *(const float4*)(x + (long)row * DEMB + t * 4);
  ln_body(v, g, b, xn, row, t, red, xupd ? xupd + (long)row * DEMB : nullptr);
}

// ---------------------------------------------------------------- MLP2 reduce + X update + LN(next/final)
__global__ void __launch_bounds__(256)
redln_k(const float* __restrict__ P, const float* __restrict__ bm2,
        float* __restrict__ X, const float* __restrict__ g,
        const float* __restrict__ b, bf16_t* __restrict__ xn) {
  __shared__ float red[4];
  const int row = blockIdx.x, t = threadIdx.x;
  const long i = (long)row * 1024 + t * 4;
  float4 x = *(float4*)(X + i);
  #pragma unroll
  for (int z = 0; z < 4; ++z) {
    float4 p = *(const float4*)(P + (long)z * 1048576 + i);
    x.x += p.x; x.y += p.y; x.z += p.z; x.w += p.w;
  }
  float4 bb = *(const float4*)(bm2 + t * 4);
  x.x += bb.x; x.y += bb.y; x.z += bb.z; x.w += bb.w;
  *(float4*)(X + i) = x;
  ln_body(x, g, b, xn, row, t, red, nullptr);
}

// ---------------------------------------------------------------- fused all-weights transpose-convert
// 128x64 tile: float4 loads -> fp32 [128][65] LDS -> NONTEMPORAL u32x4 bf16
// stores (64 B contiguous per instruction; nt bypasses L2/L3 write-allocate).
__device__ __forceinline__ void tconv_tile(const float* __restrict__ ip,
                                           bf16_t* __restrict__ op,
                                           int R, int C, int rx, int ry,
                                           float (*tf)[65]) {
  const int c0 = rx * 64, r0 = ry * 128;
  const int t = threadIdx.x;
  #pragma unroll
  for (int p = 0; p < 8; ++p) {
    const int i = p * 256 + t;
    const int r = i >> 4, c4 = (i & 15) * 4;
    const float4 v = *(const float4*)(ip + (long)(r0 + r) * C + (c0 + c4));
    *(float4*)&tf[r][c4] = v;
  }
  __syncthreads();
  const int nn = t >> 2;          // output column 0..63
  const int sub = t & 3;          // 8-row unit within each 32-row group
  #pragma unroll
  for (int q2 = 0; q2 < 4; ++q2) {
    const int base = q2 * 32 + sub * 8;
    u32x4 w;
    #pragma unroll
    for (int q = 0; q < 4; ++q) {
      PackU u;
      u.h[0] = (bf16_t)tf[base + 2 * q][nn];
      u.h[1] = (bf16_t)tf[base + 2 * q + 1][nn];
      w[q] = u.u;
    }
    __builtin_nontemporal_store(w,
        (u32x4*)(op + (long)(c0 + nn) * R + (r0 + base)));
  }
}

__global__ void __launch_bounds__(256)
tconvall_k(const float* __restrict__ Wq, const float* __restrict__ Wk,
           const float* __restrict__ Wv, const float* __restrict__ Wo,
           const float* __restrict__ W1, const float* __restrict__ W2,
           const float* __restrict__ Wu,
           bf16_t* __restrict__ WTqk, bf16_t* __restrict__ WTv,
           bf16_t* __restrict__ WTo, bf16_t* __restrict__ WT1,
           bf16_t* __restrict__ WT2, bf16_t* __restrict__ WTu) {
  __shared__ float tf[128][65];
  const long DD = (long)DEMB * DEMB;
  const int b = blockIdx.x;
  const float* ip; bf16_t* op; int R, C, rx, ry;
  if (b < 16384) {                       // Wq|Wk: 128 z x (8 ry x 16 rx)
    const int z = b >> 7, rem = b & 127; ry = rem >> 4; rx = rem & 15;
    R = 1024; C = 1024;
    const int l = z >> 5, i = z & 31;
    ip = (i < NHEAD) ? (Wq + (long)(l * NHEAD + i) * DD)
                     : (Wk + (long)(l * NHEAD + i - NHEAD) * DD);
    op = WTqk + (long)z * DD;
  } else if (b < 16896) {                // Wv: 64 z x (8 ry x 1 rx)
    const int idx = b - 16384; const int z = idx >> 3; ry = idx & 7; rx = 0;
    R = 1024; C = 64;
    ip = Wv + (long)z * 65536; op = WTv + (long)z * 65536;
  } else if (b < 16960) {                // Wo (rows 0..127): 4 z x (1 ry x 16 rx)
    const int idx = b - 16896; const int z = idx >> 4; ry = 0; rx = idx & 15;
    R = 128; C = 1024;
    ip = Wo + (long)z * DD; op = WTo + (long)z * 131072;
  } else if (b < 19008) {                // W1: 4 z x (8 ry x 64 rx)
    const int idx = b - 16960; const int z = idx >> 9, rem = idx & 511;
    ry = rem >> 6; rx = rem & 63;
    R = 1024; C = 4096;
    ip = W1 + (long)z * 4194304; op = WT1 + (long)z * 4194304;
  } else if (b < 21056) {                // W2: 4 z x (32 ry x 16 rx)
    const int idx = b - 19008; const int z = idx >> 9, rem = idx & 511;
    ry = rem >> 4; rx = rem & 15;
    R = 4096; C = 1024;
    ip = W2 + (long)z * 4194304; op = WT2 + (long)z * 4194304;
  } else {                               // Wu: 8 ry x 500 rx
    const int idx = b - 21056; ry = idx / 500; rx = idx - ry * 500;
    R = 1024; C = 32000;
    ip = Wu; op = WTu;
  }
  tconv_tile(ip, op, R, C, rx, ry, tf);
}

// ---------------------------------------------------------------- 128x128 GEMM (m97 structure)
// MODE: 1 fp32 +=, 2 fp32, 3 gelu->bf16.
template<int MODE, int BN, bool CAUSAL, bool TRIMK>
__global__ void __launch_bounds__(256)
gemm_k(const bf16_t* __restrict__ A, const bf16_t* __restrict__ B,
       const float* __restrict__ bias, void* __restrict__ Cv,
       int M, int N, int K, int lda, int ldb,
       long aB, long bB, long cB, int biasB) {
  __shared__ bf16_t lsA[128 * 32];
  __shared__ bf16_t lsB[BN * 32];

  const int t = threadIdx.x;
  const int bz = blockIdx.z;
  const int m0 = blockIdx.y * 128;
  const int n0 = blockIdx.x * BN;
  if (CAUSAL && n0 > m0 + 127) return;

  const bf16_t* Ap = A + (long)bz * aB;
  const bf16_t* Bp = B + (long)bz * bB;
  const int kEnd = TRIMK ? min(K, m0 + 128) : K;

  constexpr int NS = BN / 32;
  const int lane = t & 63;
  const int wid = t >> 6;
  const int wr = (wid >> 1) * 64;
  const int wc = (wid & 1) * (BN / 2);
  const int fr = lane & 15, fg = lane >> 4;
  const int srow = lane >> 2;
  const int skc  = (lane & 3) * 8;

  f32x4 acc[4][NS] = {};

  for (int k0 = 0; k0 < kEnd; k0 += 32) {
    if (k0) __syncthreads();
    #pragma unroll
    for (int i = 0; i < 2; ++i) {
      const int seg = wid * 2 + i;
      gload_lds16(Ap + (long)(m0 + seg * 16 + srow) * lda + (k0 + skc),
                  lsA + seg * 512);
    }
    if (BN == 128) {
      #pragma unroll
      for (int i = 0; i < 2; ++i) {
        const int seg = wid * 2 + i;
        gload_lds16(Bp + (long)(n0 + seg * 16 + srow) * ldb + (k0 + skc),
                    lsB + seg * 512);
      }
    } else {
      gload_lds16(Bp + (long)(n0 + wid * 16 + srow) * ldb + (k0 + skc),
                  lsB + wid * 512);
    }
    __syncthreads();

    bf16x8 af[4], bfv[NS];
    #pragma unroll
    for (int ms = 0; ms < 4; ++ms)
      af[ms] = *(const bf16x8*)(lsA + (wr + ms * 16 + fr) * 32 + fg * 8);
    #pragma unroll
    for (int ns = 0; ns < NS; ++ns)
      bfv[ns] = *(const bf16x8*)(lsB + (wc + ns * 16 + fr) * 32 + fg * 8);
    #pragma unroll
    for (int ms = 0; ms < 4; ++ms)
      #pragma unroll
      for (int ns = 0; ns < NS; ++ns)
        acc[ms][ns] = __builtin_amdgcn_mfma_f32_16x16x32_bf16(
            af[ms], bfv[ns], acc[ms][ns], 0, 0, 0);
  }

  #pragma unroll
  for (int ms = 0; ms < 4; ++ms) {
    #pragma unroll
    for (int ns = 0; ns < NS; ++ns) {
      const int col = n0 + wc + ns * 16 + fr;
      const float bvv = bias ? bias[(long)bz * biasB + col] : 0.0f;
      #pragma unroll
      for (int r = 0; r < 4; ++r) {
        const int row = m0 + wr + ms * 16 + fg * 4 + r;
        float v = acc[ms][ns][r] + bvv;
        if (MODE == 1) {
          ((float*)Cv)[(long)bz * cB + (long)row * N + col] += v;
        } else if (MODE == 2) {
          ((float*)Cv)[(long)bz * cB + (long)row * N + col] = v;
        } else {
          float gl = 0.5f * v * (1.0f + tanhf(0.7978845608028654f * (v + 0.044715f * v * v * v)));
          ((bf16_t*)Cv)[(long)bz * cB + (long)row * N + col] = (bf16_t)gl;
        }
      }
    }
  }
}

// ---------------------------------------------------------------- 256x256 8-phase GEMM (m201 template)
#define GPHASE(buf, mh, nh, STAGE, VM) do {                                            \
  bf16x8 af[4][2], bfv[2][2];                                                          \
  _Pragma("unroll") for (int mf = 0; mf < 4; ++mf) {                                   \
    const int r = wm * 128 + ((mh) * 4 + mf) * 16 + (lane & 15);                       \
    _Pragma("unroll") for (int ks = 0; ks < 2; ++ks) {                                 \
      const int slot = ks * 4 + (lane >> 4);                                           \
      af[mf][ks] = *(const bf16x8*)(lds + (buf) * 32768 + r * 64 +                     \
                                    ((slot ^ (r & 7)) << 3)); } }                      \
  _Pragma("unroll") for (int nf = 0; nf < 2; ++nf) {                                   \
    const int r = wn * 64 + ((nh) * 2 + nf) * 16 + (lane & 15);                        \
    _Pragma("unroll") for (int ks = 0; ks < 2; ++ks) {                                 \
      const int slot = ks * 4 + (lane >> 4);                                           \
      bfv[nf][ks] = *(const bf16x8*)(lds + (buf) * 32768 + 16384 + r * 64 +            \
                                     ((slot ^ (r & 7)) << 3)); } }                     \
  STAGE;                                                                               \
  __builtin_amdgcn_s_barrier();                                                        \
  asm volatile("s_waitcnt lgkmcnt(0)" ::: "memory");                                   \
  __builtin_amdgcn_sched_barrier(0);                                                   \
  __builtin_amdgcn_s_setprio(1);                                                       \
  _Pragma("unroll") for (int mf = 0; mf < 4; ++mf)                                     \
    _Pragma("unroll") for (int nf = 0; nf < 2; ++nf)                                   \
      _Pragma("unroll") for (int ks = 0; ks < 2; ++ks)                                 \
        acc[(mh) * 4 + mf][(nh) * 2 + nf] = __builtin_amdgcn_mfma_f32_16x16x32_bf16(   \
            af[mf][ks], bfv[nf][ks], acc[(mh) * 4 + mf][(nh) * 2 + nf], 0, 0, 0);      \
  __builtin_amdgcn_s_setprio(0);                                                       \
  VM;                                                                                  \
  __builtin_amdgcn_s_barrier();                                                        \
} while (0)

// VZ >= 0 (unpacked): blockIdx.z == VZ computes a side-GEMM (A2/B2/bias2) with
// transposed uint2 store into Cv2[n][m]. PACKED: 1-D grid of 176 blocks:
// ids 0..15 = side-GEMM tiles; ids 16..175 = causal-active score tiles.
template<int MODE, bool CAUSAL, int VZ, bool PACKED>
__global__ void __launch_bounds__(512, 1)
gemm256_k(const bf16_t* __restrict__ A, const bf16_t* __restrict__ B,
          const float* __restrict__ bias, void* __restrict__ Cv,
          int M, int N, int K, long aB, long bB, long cB, int biasB,
          const bf16_t* __restrict__ A2, const bf16_t* __restrict__ B2,
          const float* __restrict__ bias2, bf16_t* __restrict__ Cv2) {
  __shared__ bf16_t lds[65536];

  const int t = threadIdx.x;
  const int lane = t & 63, w = t >> 6;
  const int wm = w >> 2, wn = w & 3;
  int m0, n0, zz; bool vm;
  if (PACKED) {
    const int id = blockIdx.x;
    if (id < 16) {
      vm = true; zz = 0;
      m0 = (id >> 2) * 256; n0 = (id & 3) * 256;
    } else {
      vm = false;
      const int idd = id - 16;
      zz = idd & 15;
      const int pi = idd >> 4;
      const int by = (pi >= 1) + (pi >= 3) + (pi >= 6);
      const int bx = pi - (by * (by + 1)) / 2;
      m0 = by * 256; n0 = bx * 256;
    }
  } else {
    zz = blockIdx.z; m0 = blockIdx.y * 256; n0 = blockIdx.x * 256;
    vm = (VZ >= 0) && (zz == VZ);
    if (CAUSAL && !vm && n0 > m0 + 255) return;
  }

  const bf16_t* Ap = vm ? A2 : A + (long)zz * aB;
  const bf16_t* Bp = vm ? B2 : B + (long)zz * bB;
  const int NT = K >> 6;

  f32x4 acc[8][4] = {};

  auto stA = [&](int half, int kt, int buf) {
    #pragma unroll
    for (int rr = 0; rr < 2; ++rr) {
      const int rw0 = rr * 64 + w * 8;
      const int row0 = ((rw0 >> 6) << 7) | (half << 6) | (rw0 & 63);
      const int r = row0 + (lane >> 3);
      const int slot = lane & 7;
      gload_lds16(Ap + (long)(m0 + r) * K + (kt << 6) + ((slot ^ (r & 7)) << 3),
                  lds + buf * 32768 + row0 * 64);
    }
  };
  auto stB = [&](int half, int kt, int buf) {
    #pragma unroll
    for (int rr = 0; rr < 2; ++rr) {
      const int rw0 = rr * 64 + w * 8;
      const int row0 = ((rw0 >> 5) << 6) | (half << 5) | (rw0 & 31);
      const int r = row0 + (lane >> 3);
      const int slot = lane & 7;
      gload_lds16(Bp + (long)(n0 + r) * K + (kt << 6) + ((slot ^ (r & 7)) << 3),
                  lds + buf * 32768 + 16384 + row0 * 64);
    }
  };

  stB(0, 0, 0); stA(0, 0, 0); stA(1, 0, 0); stB(1, 0, 0);
  stB(0, 1, 1); stA(0, 1, 1);
  asm volatile("s_waitcnt vmcnt(4)" ::: "memory");
  __builtin_amdgcn_s_barrier();

  for (int it = 0; it < (NT >> 1); ++it) {
    const int tt = it * 2;
    const int s1 = min(tt + 1, NT - 1);
    const int s2 = min(tt + 2, NT - 1);
    const int s3 = min(tt + 3, NT - 1);
    GPHASE(0, 0, 0, { stA(1, s1, 1); }, );
    GPHASE(0, 1, 0, { stB(1, s1, 1); }, );
    GPHASE(0, 0, 1, { stB(0, s2, 0); }, );
    GPHASE(0, 1, 1, { stA(0, s2, 0); }, asm volatile("s_waitcnt vmcnt(4)" ::: "memory"));
    GPHASE(1, 0, 0, { stA(1, s2, 0); }, );
    GPHASE(1, 1, 0, { stB(1, s2, 0); }, );
    GPHASE(1, 0, 1, { stB(0, s3, 1); }, );
    GPHASE(1, 1, 1, { stA(0, s3, 1); }, asm volatile("s_waitcnt vmcnt(4)" ::: "memory"));
  }
  asm volatile("s_waitcnt vmcnt(0)" ::: "memory");

  #pragma unroll
  for (int mf = 0; mf < 8; ++mf) {
    #pragma unroll
    for (int nf = 0; nf < 4; ++nf) {
      const int col = n0 + wn * 64 + nf * 16 + (lane & 15);
      const int row0 = m0 + wm * 128 + mf * 16 + (lane >> 4) * 4;
      if (vm) {
        const float bvv = bias2[col];
        PackU p0, p1;
        p0.h[0] = (bf16_t)(acc[mf][nf][0] + bvv);
        p0.h[1] = (bf16_t)(acc[mf][nf][1] + bvv);
        p1.h[0] = (bf16_t)(acc[mf][nf][2] + bvv);
        p1.h[1] = (bf16_t)(acc[mf][nf][3] + bvv);
        uint2 st; st.x = p0.u; st.y = p1.u;
        *(uint2*)(Cv2 + (long)col * M + row0) = st;
      } else {
        const float bvv = bias ? bias[(long)zz * biasB + col] : 0.0f;
        #pragma unroll
        for (int r = 0; r < 4; ++r) {
          const float v = acc[mf][nf][r] + bvv;
          if (MODE == 0)
            ((bf16_t*)Cv)[(long)zz * cB + (long)(row0 + r) * N + col] = (bf16_t)v;
          else
            ((float*)Cv)[(long)zz * cB + (long)(row0 + r) * N + col] = v;
        }
      }
    }
  }
}

// ---------------------------------------------------------------- softmax: 4 rows/block, wave-per-row butterfly
__global__ void __launch_bounds__(256)
smax_k(const bf16_t* __restrict__ s, const bf16_t* __restrict__ V,
       bf16_t* __restrict__ Yb) {
  __shared__ float pl[4][1024];
  const int qb = blockIdx.x, h = blockIdx.y, t = threadIdx.x;
  const int w = t >> 6, lane = t & 63;
  const int q = qb * 4 + w;
  const bf16_t* sr = s + ((long)h * SEQ + q) * SEQ;
  const int L = q + 1;
  const float scale = 0.03125f;
  float e[16];
  float m = -1e30f;
  #pragma unroll
  for (int c = 0; c < 4; ++c) {
    B4U bb; bb.u = *(const uint2*)(sr + lane * 16 + c * 4);
    #pragma unroll
    for (int j = 0; j < 4; ++j) {
      const float x = (float)bb.h[j] * scale;
      e[c * 4 + j] = x;
      if (lane * 16 + c * 4 + j < L) m = fmaxf(m, x);
    }
  }
  #pragma unroll
  for (int o = 32; o > 0; o >>= 1) m = fmaxf(m, __shfl_xor(m, o, 64));
  float sum = 0.0f;
  #pragma unroll
  for (int i = 0; i < 16; ++i) {
    e[i] = (lane * 16 + i < L) ? expf(e[i] - m) : 0.0f;
    sum += e[i];
  }
  #pragma unroll
  for (int o = 32; o > 0; o >>= 1) sum += __shfl_xor(sum, o, 64);
  const float inv = 1.0f / sum;

  if (h != NHEAD - 1) {
    const bf16_t* vc = V + (long)h * 64 * SEQ + lane * 16;
    float d = 0.0f;
    #pragma unroll
    for (int c = 0; c < 4; ++c) {
      B4U vv; vv.u = *(const uint2*)(vc + c * 4);
      #pragma unroll
      for (int j = 0; j < 4; ++j) d += e[c * 4 + j] * (float)vv.h[j];
    }
    #pragma unroll
    for (int o = 32; o > 0; o >>= 1) d += __shfl_xor(d, o, 64);
    if (lane == 0) Yb[(long)q * 128 + h] = (bf16_t)(d * inv);
  } else {
    #pragma unroll
    for (int c = 0; c < 4; ++c)
      *(float4*)&pl[w][lane * 16 + c * 4] = *(float4*)&e[c * 4];
    __syncthreads();
    const int c = t & 63, r = t >> 6;
    const int qq = qb * 4 + r;
    const bf16_t* vr = V + ((long)(NHEAD - 1) * 64 + c) * SEQ;
    float d = 0.0f;
    for (int kk = 0; kk < 1024; kk += 8) {
      bf16x8 v8 = *(const bf16x8*)(vr + kk);
      #pragma unroll
      for (int j = 0; j < 8; ++j) d += pl[r][kk + j] * (float)v8[j];
    }
    float sr2 = 0.0f;
    for (int kk = t & 63; kk < 1024; kk += 64) sr2 += pl[r][kk];
    #pragma unroll
    for (int o = 32; o > 0; o >>= 1) sr2 += __shfl_xor(sr2, o, 64);
    Yb[(long)qq * 128 + 15 + c] = (bf16_t)(d / sr2);
  }
}

// ---------------------------------------------------------------- final vocab softmax: bf16 logits -> fp32 probs
__global__ void __launch_bounds__(1024)
vsmax_k(const bf16_t* __restrict__ lg, float* __restrict__ out) {
  __shared__ float rm[16], rs[16];
  const int row = blockIdx.x, t = threadIdx.x;
  const bf16_t* lr = lg + (long)row * NVOCAB;
  float* r = out + (long)row * NVOCAB;
  float v[32];
  float m = -1e30f;
  #pragma unroll
  for (int j = 0; j < 16; ++j) {
    const int c = 2 * (j * 1024 + t);
    if (j < 15 || t < 640) {                 // c < 32000
      PackU u; u.u = *(const u32*)(lr + c);
      v[2 * j]     = (float)u.h[0];
      v[2 * j + 1] = (float)u.h[1];
      m = fmaxf(m, fmaxf(v[2 * j], v[2 * j + 1]));
    } else {
      v[2 * j] = v[2 * j + 1] = -1e30f;
    }
  }
  float s = 0.0f;
  #pragma unroll
  for (int j = 0; j < 32; ++j) s += expf(v[j] - m);
  #pragma unroll
  for (int o = 32; o > 0; o >>= 1) {
    const float mo = __shfl_down(m, o, 64);
    const float so = __shfl_down(s, o, 64);
    const float M2 = fmaxf(m, mo);
    s = s * expf(m - M2) + so * expf(mo - M2);
    m = M2;
  }
  if ((t & 63) == 0) { rm[t >> 6] = m; rs[t >> 6] = s; }
  __syncthreads();
  float M = -1e30f;
  #pragma unroll
  for (int i = 0; i < 16; ++i) M = fmaxf(M, rm[i]);
  float S = 0.0f;
  #pragma unroll
  for (int i = 0; i < 16; ++i) S += rs[i] * expf(rm[i] - M);
  const float inv = 1.0f / S;
  #pragma unroll
  for (int j = 0; j < 16; ++j) {
    const int c = 2 * (j * 1024 + t);
    if (j < 15 || t < 640) {
      float2 p; p.x = expf(v[2 * j] - M) * inv; p.y = expf(v[2 * j + 1] - M) * inv;
      *(float2*)(r + c) = p;
    }
  }
}

// ---------------------------------------------------------------- launch
extern "C" void kernel_launch(void* const* d_in, const int* in_sizes, int n_in,
                              void* d_out, int out_size, void* d_ws, size_t ws_size,
                              hipStream_t stream) {
  (void)in_sizes; (void)n_in; (void)out_size; (void)ws_size;
  const int*   x_ids = (const int*)  d_in[0];
  const float* wemb  = (const float*)d_in[1];
  const float* pemb  = (const float*)d_in[2];
  const float* Wq    = (const float*)d_in[3];
  const float* bq    = (const float*)d_in[4];
  const float* Wk    = (const float*)d_in[5];
  const float* bk    = (const float*)d_in[6];
  const float* Wv    = (const float*)d_in[7];
  const float* bv    = (const float*)d_in[8];
  const float* Wo    = (const float*)d_in[9];
  const float* bo    = (const float*)d_in[10];
  const float* g1    = (const float*)d_in[11];
  const float* b1    = (const float*)d_in[12];
  const float* g2    = (const float*)d_in[13];
  const float* b2    = (const float*)d_in[14];
  const float* W1    = (const float*)d_in[15];
  const float* bm1   = (const float*)d_in[16];
  const float* W2    = (const float*)d_in[17];
  const float* bm2   = (const float*)d_in[18];
  const float* gf    = (const float*)d_in[19];
  const float* bfin  = (const float*)d_in[20];
  const float* Wu    = (const float*)d_in[21];
  const float* bu    = (const float*)d_in[22];

  char* ws = (char*)d_ws;
  float*  X    = (float*) ws;                           //   0- 4  fp32 residual
  bf16_t* ACT  = (bf16_t*)(ws + (4u   << 20));          //   4- 6
  bf16_t* VbT  = (bf16_t*)(ws + (6u   << 20));          //   6- 8  [h*64+v][seq]
  bf16_t* Yb   = (bf16_t*)(ws + (10u  << 20));          //  10-10.25 [q][128]
  bf16_t* H1   = (bf16_t*)(ws + (12u  << 20));          //  12-20
  bf16_t* QKb  = (bf16_t*)(ws + (20u  << 20));          //  20-84 [z=32][q][e]
  float*  PART = (float*) (ws + (84u  << 20));          //  84-100 MLP2 split-K
  float*  BIAS = (float*) (ws + (100u << 20));          // 100-100.5 [l*32+i][e]
  bf16_t* WTqk = (bf16_t*)(ws + (128u << 20));          // 128-384 [l*32+i][e][d]
  bf16_t* LOGIT= (bf16_t*)(ws + (128u << 20));          // 128-190.5 (WTqk[0] dead by unembed)
  bf16_t* WTv  = (bf16_t*)(ws + (384u << 20));          // 384-392 [l*16+h][v][d]
  bf16_t* WTo  = (bf16_t*)(ws + (392u << 20));          // 392-393 [l][e][128]
  bf16_t* WT1  = (bf16_t*)(ws + (400u << 20));          // 400-432 [l][dm][d]
  bf16_t* WT2  = (bf16_t*)(ws + (432u << 20));          // 432-464 [l][d][dm]
  bf16_t* WTu  = (bf16_t*)(ws + (464u << 20));          // 464-526.5 [v][d]

  bf16_t* Sb  = (bf16_t*)d_out;                         // 32 MiB raw scores
  float*  OUT = (float*)d_out;

  const long DD = (long)DEMB * DEMB;
  const long SD = (long)SEQ * DEMB;

  // ---------------- prologue (2 launches)
  embedlnbias_k<<<SEQ + 128 + 64, 256, 0, stream>>>(
      x_ids, wemb, pemb, g1, b1, X, ACT, bq, bk, BIAS, Yb);
  tconvall_k<<<25056, 256, 0, stream>>>(Wq, Wk, Wv, Wo, W1, W2, Wu,
                                        WTqk, WTv, WTo, WT1, WT2, WTu);

  for (int l = 0; l < NLAYER; ++l) {
    // Q|K projection: z = 32 heads (512 blocks = 2 clean block-waves)
    gemm256_k<0, false, -1, false><<<dim3(4, 4, 32), 512, 0, stream>>>(
        ACT, WTqk + (long)l * 32 * DD, BIAS + (long)l * 32 * DEMB, QKb,
        SEQ, DEMB, DEMB, 0L, DD, SD, DEMB,
        nullptr, nullptr, nullptr, nullptr);

    // scores (160 causal-active tiles) + V projection (16 tiles): 176 packed blocks
    gemm256_k<0, true, 0, true><<<dim3(176), 512, 0, stream>>>(
        QKb, QKb + (long)NHEAD * SD, nullptr, Sb,
        SEQ, SEQ, DEMB, SD, SD, (long)SEQ * SEQ, 0,
        ACT, WTv + (long)l * DD, bv + (long)l * NHEAD * DVDIM, VbT);

    // softmax (4 rows/block) + full AV -> Yb
    smax_k<<<dim3(SEQ / 4, NHEAD), 256, 0, stream>>>(Sb, VbT, Yb);

    // x += y @ Wo + bo (K=128), BN=64 -> 128 blocks
    gemm_k<1, 64, false, false><<<dim3(16, 8, 1), 256, 0, stream>>>(
        Yb, WTo + (long)l * DEMB * 128, bo + (long)l * DEMB, X,
        SEQ, DEMB, 128, 128, 128, 0L, 0L, 0L, 0);

    // LN2
    ln_k<<<SEQ, 256, 0, stream>>>(X, g2 + l * DEMB, b2 + l * DEMB, ACT, X);

    // MLP1: gelu(xn2 @ W1 + bm1)
    gemm_k<3, 128, false, false><<<dim3(32, 8, 1), 256, 0, stream>>>(
        ACT, WT1 + (long)l * DMLP * DEMB, bm1 + (long)l * DMLP, H1,
        SEQ, DMLP, DEMB, DEMB, DEMB, 0L, 0L, 0L, 0);
    // MLP2 split-K
    gemm_k<2, 128, false, false><<<dim3(8, 8, 4), 256, 0, stream>>>(
        H1, WT2 + (long)l * DEMB * DMLP, nullptr, PART,
        SEQ, DEMB, 1024, DMLP, DMLP, 1024L, 1024L, (long)SEQ * DEMB, 0);
    // reduce + X update + LN (next layer's LN1 or final LN)
    if (l < NLAYER - 1)
      redln_k<<<SEQ, 256, 0, stream>>>(PART, bm2 + (long)l * DEMB, X,
                                       g1 + (l + 1) * DEMB, b1 + (l + 1) * DEMB, ACT);
    else
      redln_k<<<SEQ, 256, 0, stream>>>(PART, bm2 + (long)l * DEMB, X, gf, bfin, ACT);
  }

  // unembed -> bf16 logits (into dead WTqk[0] space), then softmax -> fp32 probs
  gemm256_k<0, false, -1, false><<<dim3(125, 4, 1), 512, 0, stream>>>(
      ACT, WTu, bu, LOGIT, SEQ, NVOCAB, DEMB, 0L, 0L, 0L, 0,
      nullptr, nullptr, nullptr, nullptr);
  vsmax_k<<<SEQ, 1024, 0, stream>>>(LOGIT, OUT);
}

// Round 15
// 1367.582 us; speedup vs baseline: 1.0224x; 1.0224x over previous
//
#include <hip/hip_runtime.h>

typedef __bf16 bf16_t;
typedef __bf16 bf16x8 __attribute__((ext_vector_type(8)));
typedef float f32x4 __attribute__((ext_vector_type(4)));
typedef unsigned int u32;

#define SEQ    1024
#define DEMB   1024
#define NHEAD  16
#define DVDIM  64
#define DMLP   4096
#define NVOCAB 32000
#define NLAYER 4

typedef const __attribute__((address_space(1))) void gas_t;
typedef __attribute__((address_space(3))) void las_t;

__device__ __forceinline__ void gload_lds16(const void* g, void* l) {
  __builtin_amdgcn_global_load_lds((gas_t*)g, (las_t*)l, 16, 0, 0);
}

union PackU { bf16_t h[2]; u32 u; };
union B4U  { uint2 u; bf16_t h[4]; };

// ---------------------------------------------------------------- reductions
__device__ __forceinline__ float blockSum(float v, float* red) {
  #pragma unroll
  for (int o = 32; o > 0; o >>= 1) v += __shfl_down(v, o, 64);
  __syncthreads();
  if ((threadIdx.x & 63) == 0) red[threadIdx.x >> 6] = v;
  __syncthreads();
  return (red[0] + red[1]) + (red[2] + red[3]);
}

// ---------------------------------------------------------------- LN body
__device__ __forceinline__ void ln_body(float4 v, const float* __restrict__ g,
                                        const float* __restrict__ b,
                                        bf16_t* __restrict__ xn, int row, int t,
                                        float* red, float* xupd_row) {
  float mu = blockSum(v.x + v.y + v.z + v.w, red) * (1.0f / DEMB);
  float dx = v.x - mu, dy = v.y - mu, dz = v.z - mu, dw = v.w - mu;
  float var = blockSum(dx * dx + dy * dy + dz * dz + dw * dw, red) * (1.0f / DEMB);
  float inv = 1.0f / sqrtf(var);
  float4 gv = *(const float4*)(g + t * 4);
  float4 bv = *(const float4*)(b + t * 4);
  float o0 = gv.x * dx * inv + bv.x;
  float o1 = gv.y * dy * inv + bv.y;
  float o2 = gv.z * dz * inv + bv.z;
  float o3 = gv.w * dw * inv + bv.w;
  PackU p0, p1;
  p0.h[0] = (bf16_t)o0; p0.h[1] = (bf16_t)o1;
  p1.h[0] = (bf16_t)o2; p1.h[1] = (bf16_t)o3;
  uint2 st; st.x = p0.u; st.y = p1.u;
  *(uint2*)(xn + (long)row * DEMB + t * 4) = st;
  if (xupd_row) {
    float4 nv; nv.x = v.x + o0; nv.y = v.y + o1; nv.z = v.z + o2; nv.w = v.w + o3;
    *(float4*)(xupd_row + t * 4) = nv;
  }
}

// ---------------------------------------------------------------- prologue combo: embed+LN1(l0) | bias concat | Yb zero
__global__ void __launch_bounds__(256)
embedlnbias_k(const int* __restrict__ ids, const float* __restrict__ we,
              const float* __restrict__ pe, const float* __restrict__ g,
              const float* __restrict__ b, float* __restrict__ x,
              bf16_t* __restrict__ xn,
              const float* __restrict__ bq, const float* __restrict__ bk,
              float* __restrict__ bias_out, bf16_t* __restrict__ y) {
  __shared__ float red[4];
  const int bidx = blockIdx.x, t = threadIdx.x;
  if (bidx < SEQ) {
    const int row = bidx;
    const long id = ids[row];
    float4 a = *(const float4*)(we + id * (long)DEMB + t * 4);
    float4 p = *(const float4*)(pe + (long)row * DEMB + t * 4);
    float4 v; v.x = a.x + p.x; v.y = a.y + p.y; v.z = a.z + p.z; v.w = a.w + p.w;
    *(float4*)(x + (long)row * DEMB + t * 4) = v;
    ln_body(v, g, b, xn, row, t, red, nullptr);
  } else if (bidx < SEQ + 128) {
    const int z = bidx - SEQ;
    const int l = z >> 5, i = z & 31;
    const float* src = (i < NHEAD) ? (bq + (long)(l * NHEAD + i) * DEMB)
                                   : (bk + (long)(l * NHEAD + i - NHEAD) * DEMB);
    *(float4*)(bias_out + (long)z * DEMB + t * 4) = *(const float4*)(src + t * 4);
  } else {
    const int z = bidx - SEQ - 128;
    *(uint4*)((char*)y + ((long)z * 256 + t) * 16) = uint4{0, 0, 0, 0};
  }
}

// ---------------------------------------------------------------- layernorm (mid-layer ln2)
__global__ void __launch_bounds__(256)
ln_k(const float* __restrict__ x, const float* __restrict__ g,
     const float* __restrict__ b, bf16_t* __restrict__ xn,
     float* __restrict__ xupd) {
  __shared__ float red[4];
  const int row = blockIdx.x, t = threadIdx.x;
  float4 v = *(const float4*)(x + (long)row * DEMB + t * 4);
  ln_body(v, g, b, xn, row, t, red, xupd ? xupd + (long)row * DEMB : nullptr);
}

// ---------------------------------------------------------------- MLP2 reduce + X update + LN(next/final)
__global__ void __launch_bounds__(256)
redln_k(const float* __restrict__ P, const float* __restrict__ bm2,
        float* __restrict__ X, const float* __restrict__ g,
        const float* __restrict__ b, bf16_t* __restrict__ xn) {
  __shared__ float red[4];
  const int row = blockIdx.x, t = threadIdx.x;
  const long i = (long)row * 1024 + t * 4;
  float4 x = *(float4*)(X + i);
  #pragma unroll
  for (int z = 0; z < 4; ++z) {
    float4 p = *(const float4*)(P + (long)z * 1048576 + i);
    x.x += p.x; x.y += p.y; x.z += p.z; x.w += p.w;
  }
  float4 bb = *(const float4*)(bm2 + t * 4);
  x.x += bb.x; x.y += bb.y; x.z += bb.z; x.w += bb.w;
  *(float4*)(X + i) = x;
  ln_body(x, g, b, xn, row, t, red, nullptr);
}

// ---------------------------------------------------------------- fused all-weights transpose-convert
// 128x64 tile: float4 loads -> fp32 [128][65] LDS -> plain uint4 bf16 stores
// (64 B contiguous per instruction; L2 merges into full lines — nt stores
// measured WORSE: bypass L2 write-combining, +30% HBM write traffic).
__device__ __forceinline__ void tconv_tile(const float* __restrict__ ip,
                                           bf16_t* __restrict__ op,
                                           int R, int C, int rx, int ry,
                                           float (*tf)[65]) {
  const int c0 = rx * 64, r0 = ry * 128;
  const int t = threadIdx.x;
  #pragma unroll
  for (int p = 0; p < 8; ++p) {
    const int i = p * 256 + t;
    const int r = i >> 4, c4 = (i & 15) * 4;
    const float4 v = *(const float4*)(ip + (long)(r0 + r) * C + (c0 + c4));
    *(float4*)&tf[r][c4] = v;
  }
  __syncthreads();
  const int nn = t >> 2;          // output column 0..63
  const int sub = t & 3;          // 8-row unit within each 32-row group
  #pragma unroll
  for (int q2 = 0; q2 < 4; ++q2) {
    const int base = q2 * 32 + sub * 8;
    u32 w[4];
    #pragma unroll
    for (int q = 0; q < 4; ++q) {
      PackU u;
      u.h[0] = (bf16_t)tf[base + 2 * q][nn];
      u.h[1] = (bf16_t)tf[base + 2 * q + 1][nn];
      w[q] = u.u;
    }
    *(uint4*)(op + (long)(c0 + nn) * R + (r0 + base)) = *(uint4*)&w[0];
  }
}

__global__ void __launch_bounds__(256)
tconvall_k(const float* __restrict__ Wq, const float* __restrict__ Wk,
           const float* __restrict__ Wv, const float* __restrict__ Wo,
           const float* __restrict__ W1, const float* __restrict__ W2,
           const float* __restrict__ Wu,
           bf16_t* __restrict__ WTqk, bf16_t* __restrict__ WTv,
           bf16_t* __restrict__ WTo, bf16_t* __restrict__ WT1,
           bf16_t* __restrict__ WT2, bf16_t* __restrict__ WTu) {
  __shared__ float tf[128][65];
  const long DD = (long)DEMB * DEMB;
  const int b = blockIdx.x;
  const float* ip; bf16_t* op; int R, C, rx, ry;
  if (b < 16384) {                       // Wq|Wk: 128 z x (8 ry x 16 rx)
    const int z = b >> 7, rem = b & 127; ry = rem >> 4; rx = rem & 15;
    R = 1024; C = 1024;
    const int l = z >> 5, i = z & 31;
    ip = (i < NHEAD) ? (Wq + (long)(l * NHEAD + i) * DD)
                     : (Wk + (long)(l * NHEAD + i - NHEAD) * DD);
    op = WTqk + (long)z * DD;
  } else if (b < 16896) {                // Wv: 64 z x (8 ry x 1 rx)
    const int idx = b - 16384; const int z = idx >> 3; ry = idx & 7; rx = 0;
    R = 1024; C = 64;
    ip = Wv + (long)z * 65536; op = WTv + (long)z * 65536;
  } else if (b < 16960) {                // Wo (rows 0..127): 4 z x (1 ry x 16 rx)
    const int idx = b - 16896; const int z = idx >> 4; ry = 0; rx = idx & 15;
    R = 128; C = 1024;
    ip = Wo + (long)z * DD; op = WTo + (long)z * 131072;
  } else if (b < 19008) {                // W1: 4 z x (8 ry x 64 rx)
    const int idx = b - 16960; const int z = idx >> 9, rem = idx & 511;
    ry = rem >> 6; rx = rem & 63;
    R = 1024; C = 4096;
    ip = W1 + (long)z * 4194304; op = WT1 + (long)z * 4194304;
  } else if (b < 21056) {                // W2: 4 z x (32 ry x 16 rx)
    const int idx = b - 19008; const int z = idx >> 9, rem = idx & 511;
    ry = rem >> 4; rx = rem & 15;
    R = 4096; C = 1024;
    ip = W2 + (long)z * 4194304; op = WT2 + (long)z * 4194304;
  } else {                               // Wu: 8 ry x 500 rx
    const int idx = b - 21056; ry = idx / 500; rx = idx - ry * 500;
    R = 1024; C = 32000;
    ip = Wu; op = WTu;
  }
  tconv_tile(ip, op, R, C, rx, ry, tf);
}

// ---------------------------------------------------------------- 128x128 GEMM (m97 structure)
// MODE: 1 fp32 +=, 2 fp32, 3 gelu->bf16.
template<int MODE, int BN, bool CAUSAL, bool TRIMK>
__global__ void __launch_bounds__(256)
gemm_k(const bf16_t* __restrict__ A, const bf16_t* __restrict__ B,
       const float* __restrict__ bias, void* __restrict__ Cv,
       int M, int N, int K, int lda, int ldb,
       long aB, long bB, long cB, int biasB) {
  __shared__ bf16_t lsA[128 * 32];
  __shared__ bf16_t lsB[BN * 32];

  const int t = threadIdx.x;
  const int bz = blockIdx.z;
  const int m0 = blockIdx.y * 128;
  const int n0 = blockIdx.x * BN;
  if (CAUSAL && n0 > m0 + 127) return;

  const bf16_t* Ap = A + (long)bz * aB;
  const bf16_t* Bp = B + (long)bz * bB;
  const int kEnd = TRIMK ? min(K, m0 + 128) : K;

  constexpr int NS = BN / 32;
  const int lane = t & 63;
  const int wid = t >> 6;
  const int wr = (wid >> 1) * 64;
  const int wc = (wid & 1) * (BN / 2);
  const int fr = lane & 15, fg = lane >> 4;
  const int srow = lane >> 2;
  const int skc  = (lane & 3) * 8;

  f32x4 acc[4][NS] = {};

  for (int k0 = 0; k0 < kEnd; k0 += 32) {
    if (k0) __syncthreads();
    #pragma unroll
    for (int i = 0; i < 2; ++i) {
      const int seg = wid * 2 + i;
      gload_lds16(Ap + (long)(m0 + seg * 16 + srow) * lda + (k0 + skc),
                  lsA + seg * 512);
    }
    if (BN == 128) {
      #pragma unroll
      for (int i = 0; i < 2; ++i) {
        const int seg = wid * 2 + i;
        gload_lds16(Bp + (long)(n0 + seg * 16 + srow) * ldb + (k0 + skc),
                    lsB + seg * 512);
      }
    } else {
      gload_lds16(Bp + (long)(n0 + wid * 16 + srow) * ldb + (k0 + skc),
                  lsB + wid * 512);
    }
    __syncthreads();

    bf16x8 af[4], bfv[NS];
    #pragma unroll
    for (int ms = 0; ms < 4; ++ms)
      af[ms] = *(const bf16x8*)(lsA + (wr + ms * 16 + fr) * 32 + fg * 8);
    #pragma unroll
    for (int ns = 0; ns < NS; ++ns)
      bfv[ns] = *(const bf16x8*)(lsB + (wc + ns * 16 + fr) * 32 + fg * 8);
    #pragma unroll
    for (int ms = 0; ms < 4; ++ms)
      #pragma unroll
      for (int ns = 0; ns < NS; ++ns)
        acc[ms][ns] = __builtin_amdgcn_mfma_f32_16x16x32_bf16(
            af[ms], bfv[ns], acc[ms][ns], 0, 0, 0);
  }

  #pragma unroll
  for (int ms = 0; ms < 4; ++ms) {
    #pragma unroll
    for (int ns = 0; ns < NS; ++ns) {
      const int col = n0 + wc + ns * 16 + fr;
      const float bvv = bias ? bias[(long)bz * biasB + col] : 0.0f;
      #pragma unroll
      for (int r = 0; r < 4; ++r) {
        const int row = m0 + wr + ms * 16 + fg * 4 + r;
        float v = acc[ms][ns][r] + bvv;
        if (MODE == 1) {
          ((float*)Cv)[(long)bz * cB + (long)row * N + col] += v;
        } else if (MODE == 2) {
          ((float*)Cv)[(long)bz * cB + (long)row * N + col] = v;
        } else {
          float gl = 0.5f * v * (1.0f + tanhf(0.7978845608028654f * (v + 0.044715f * v * v * v)));
          ((bf16_t*)Cv)[(long)bz * cB + (long)row * N + col] = (bf16_t)gl;
        }
      }
    }
  }
}

// ---------------------------------------------------------------- 256x256 8-phase GEMM (m201 template)
#define GPHASE(buf, mh, nh, STAGE, VM) do {                                            \
  bf16x8 af[4][2], bfv[2][2];                                                          \
  _Pragma("unroll") for (int mf = 0; mf < 4; ++mf) {                                   \
    const int r = wm * 128 + ((mh) * 4 + mf) * 16 + (lane & 15);                       \
    _Pragma("unroll") for (int ks = 0; ks < 2; ++ks) {                                 \
      const int slot = ks * 4 + (lane >> 4);                                           \
      af[mf][ks] = *(const bf16x8*)(lds + (buf) * 32768 + r * 64 +                     \
                                    ((slot ^ (r & 7)) << 3)); } }                      \
  _Pragma("unroll") for (int nf = 0; nf < 2; ++nf) {                                   \
    const int r = wn * 64 + ((nh) * 2 + nf) * 16 + (lane & 15);                        \
    _Pragma("unroll") for (int ks = 0; ks < 2; ++ks) {                                 \
      const int slot = ks * 4 + (lane >> 4);                                           \
      bfv[nf][ks] = *(const bf16x8*)(lds + (buf) * 32768 + 16384 + r * 64 +            \
                                     ((slot ^ (r & 7)) << 3)); } }                     \
  STAGE;                                                                               \
  __builtin_amdgcn_s_barrier();                                                        \
  asm volatile("s_waitcnt lgkmcnt(0)" ::: "memory");                                   \
  __builtin_amdgcn_sched_barrier(0);                                                   \
  __builtin_amdgcn_s_setprio(1);                                                       \
  _Pragma("unroll") for (int mf = 0; mf < 4; ++mf)                                     \
    _Pragma("unroll") for (int nf = 0; nf < 2; ++nf)                                   \
      _Pragma("unroll") for (int ks = 0; ks < 2; ++ks)                                 \
        acc[(mh) * 4 + mf][(nh) * 2 + nf] = __builtin_amdgcn_mfma_f32_16x16x32_bf16(   \
            af[mf][ks], bfv[nf][ks], acc[(mh) * 4 + mf][(nh) * 2 + nf], 0, 0, 0);      \
  __builtin_amdgcn_s_setprio(0);                                                       \
  VM;                                                                                  \
  __builtin_amdgcn_s_barrier();                                                        \
} while (0)

// VZ >= 0 (unpacked): blockIdx.z == VZ computes a side-GEMM (A2/B2/bias2) with
// transposed uint2 store into Cv2[n][m]. PACKED: 1-D grid of 176 blocks:
// ids 0..15 = side-GEMM tiles; ids 16..175 = causal-active score tiles.
template<int MODE, bool CAUSAL, int VZ, bool PACKED>
__global__ void __launch_bounds__(512, 1)
gemm256_k(const bf16_t* __restrict__ A, const bf16_t* __restrict__ B,
          const float* __restrict__ bias, void* __restrict__ Cv,
          int M, int N, int K, long aB, long bB, long cB, int biasB,
          const bf16_t* __restrict__ A2, const bf16_t* __restrict__ B2,
          const float* __restrict__ bias2, bf16_t* __restrict__ Cv2) {
  __shared__ bf16_t lds[65536];

  const int t = threadIdx.x;
  const int lane = t & 63, w = t >> 6;
  const int wm = w >> 2, wn = w & 3;
  int m0, n0, zz; bool vm;
  if (PACKED) {
    const int id = blockIdx.x;
    if (id < 16) {
      vm = true; zz = 0;
      m0 = (id >> 2) * 256; n0 = (id & 3) * 256;
    } else {
      vm = false;
      const int idd = id - 16;
      zz = idd & 15;
      const int pi = idd >> 4;
      const int by = (pi >= 1) + (pi >= 3) + (pi >= 6);
      const int bx = pi - (by * (by + 1)) / 2;
      m0 = by * 256; n0 = bx * 256;
    }
  } else {
    zz = blockIdx.z; m0 = blockIdx.y * 256; n0 = blockIdx.x * 256;
    vm = (VZ >= 0) && (zz == VZ);
    if (CAUSAL && !vm && n0 > m0 + 255) return;
  }

  const bf16_t* Ap = vm ? A2 : A + (long)zz * aB;
  const bf16_t* Bp = vm ? B2 : B + (long)zz * bB;
  const int NT = K >> 6;

  f32x4 acc[8][4] = {};

  auto stA = [&](int half, int kt, int buf) {
    #pragma unroll
    for (int rr = 0; rr < 2; ++rr) {
      const int rw0 = rr * 64 + w * 8;
      const int row0 = ((rw0 >> 6) << 7) | (half << 6) | (rw0 & 63);
      const int r = row0 + (lane >> 3);
      const int slot = lane & 7;
      gload_lds16(Ap + (long)(m0 + r) * K + (kt << 6) + ((slot ^ (r & 7)) << 3),
                  lds + buf * 32768 + row0 * 64);
    }
  };
  auto stB = [&](int half, int kt, int buf) {
    #pragma unroll
    for (int rr = 0; rr < 2; ++rr) {
      const int rw0 = rr * 64 + w * 8;
      const int row0 = ((rw0 >> 5) << 6) | (half << 5) | (rw0 & 31);
      const int r = row0 + (lane >> 3);
      const int slot = lane & 7;
      gload_lds16(Bp + (long)(n0 + r) * K + (kt << 6) + ((slot ^ (r & 7)) << 3),
                  lds + buf * 32768 + 16384 + row0 * 64);
    }
  };

  stB(0, 0, 0); stA(0, 0, 0); stA(1, 0, 0); stB(1, 0, 0);
  stB(0, 1, 1); stA(0, 1, 1);
  asm volatile("s_waitcnt vmcnt(4)" ::: "memory");
  __builtin_amdgcn_s_barrier();

  for (int it = 0; it < (NT >> 1); ++it) {
    const int tt = it * 2;
    const int s1 = min(tt + 1, NT - 1);
    const int s2 = min(tt + 2, NT - 1);
    const int s3 = min(tt + 3, NT - 1);
    GPHASE(0, 0, 0, { stA(1, s1, 1); }, );
    GPHASE(0, 1, 0, { stB(1, s1, 1); }, );
    GPHASE(0, 0, 1, { stB(0, s2, 0); }, );
    GPHASE(0, 1, 1, { stA(0, s2, 0); }, asm volatile("s_waitcnt vmcnt(4)" ::: "memory"));
    GPHASE(1, 0, 0, { stA(1, s2, 0); }, );
    GPHASE(1, 1, 0, { stB(1, s2, 0); }, );
    GPHASE(1, 0, 1, { stB(0, s3, 1); }, );
    GPHASE(1, 1, 1, { stA(0, s3, 1); }, asm volatile("s_waitcnt vmcnt(4)" ::: "memory"));
  }
  asm volatile("s_waitcnt vmcnt(0)" ::: "memory");

  #pragma unroll
  for (int mf = 0; mf < 8; ++mf) {
    #pragma unroll
    for (int nf = 0; nf < 4; ++nf) {
      const int col = n0 + wn * 64 + nf * 16 + (lane & 15);
      const int row0 = m0 + wm * 128 + mf * 16 + (lane >> 4) * 4;
      if (vm) {
        const float bvv = bias2[col];
        PackU p0, p1;
        p0.h[0] = (bf16_t)(acc[mf][nf][0] + bvv);
        p0.h[1] = (bf16_t)(acc[mf][nf][1] + bvv);
        p1.h[0] = (bf16_t)(acc[mf][nf][2] + bvv);
        p1.h[1] = (bf16_t)(acc[mf][nf][3] + bvv);
        uint2 st; st.x = p0.u; st.y = p1.u;
        *(uint2*)(Cv2 + (long)col * M + row0) = st;
      } else {
        const float bvv = bias ? bias[(long)zz * biasB + col] : 0.0f;
        #pragma unroll
        for (int r = 0; r < 4; ++r) {
          const float v = acc[mf][nf][r] + bvv;
          if (MODE == 0)
            ((bf16_t*)Cv)[(long)zz * cB + (long)(row0 + r) * N + col] = (bf16_t)v;
          else
            ((float*)Cv)[(long)zz * cB + (long)(row0 + r) * N + col] = v;
        }
      }
    }
  }
}

// ---------------------------------------------------------------- softmax: 4 rows/block, wave-per-row butterfly
__global__ void __launch_bounds__(256)
smax_k(const bf16_t* __restrict__ s, const bf16_t* __restrict__ V,
       bf16_t* __restrict__ Yb) {
  __shared__ float pl[4][1024];
  const int qb = blockIdx.x, h = blockIdx.y, t = threadIdx.x;
  const int w = t >> 6, lane = t & 63;
  const int q = qb * 4 + w;
  const bf16_t* sr = s + ((long)h * SEQ + q) * SEQ;
  const int L = q + 1;
  const float scale = 0.03125f;
  float e[16];
  float m = -1e30f;
  #pragma unroll
  for (int c = 0; c < 4; ++c) {
    B4U bb; bb.u = *(const uint2*)(sr + lane * 16 + c * 4);
    #pragma unroll
    for (int j = 0; j < 4; ++j) {
      const float x = (float)bb.h[j] * scale;
      e[c * 4 + j] = x;
      if (lane * 16 + c * 4 + j < L) m = fmaxf(m, x);
    }
  }
  #pragma unroll
  for (int o = 32; o > 0; o >>= 1) m = fmaxf(m, __shfl_xor(m, o, 64));
  float sum = 0.0f;
  #pragma unroll
  for (int i = 0; i < 16; ++i) {
    e[i] = (lane * 16 + i < L) ? expf(e[i] - m) : 0.0f;
    sum += e[i];
  }
  #pragma unroll
  for (int o = 32; o > 0; o >>= 1) sum += __shfl_xor(sum, o, 64);
  const float inv = 1.0f / sum;

  if (h != NHEAD - 1) {
    const bf16_t* vc = V + (long)h * 64 * SEQ + lane * 16;
    float d = 0.0f;
    #pragma unroll
    for (int c = 0; c < 4; ++c) {
      B4U vv; vv.u = *(const uint2*)(vc + c * 4);
      #pragma unroll
      for (int j = 0; j < 4; ++j) d += e[c * 4 + j] * (float)vv.h[j];
    }
    #pragma unroll
    for (int o = 32; o > 0; o >>= 1) d += __shfl_xor(d, o, 64);
    if (lane == 0) Yb[(long)q * 128 + h] = (bf16_t)(d * inv);
  } else {
    #pragma unroll
    for (int c = 0; c < 4; ++c)
      *(float4*)&pl[w][lane * 16 + c * 4] = *(float4*)&e[c * 4];
    __syncthreads();
    const int c = t & 63, r = t >> 6;
    const int qq = qb * 4 + r;
    const bf16_t* vr = V + ((long)(NHEAD - 1) * 64 + c) * SEQ;
    float d = 0.0f;
    for (int kk = 0; kk < 1024; kk += 8) {
      bf16x8 v8 = *(const bf16x8*)(vr + kk);
      #pragma unroll
      for (int j = 0; j < 8; ++j) d += pl[r][kk + j] * (float)v8[j];
    }
    float sr2 = 0.0f;
    for (int kk = t & 63; kk < 1024; kk += 64) sr2 += pl[r][kk];
    #pragma unroll
    for (int o = 32; o > 0; o >>= 1) sr2 += __shfl_xor(sr2, o, 64);
    Yb[(long)qq * 128 + 15 + c] = (bf16_t)(d / sr2);
  }
}

// ---------------------------------------------------------------- final vocab softmax: bf16 logits -> fp32 probs
__global__ void __launch_bounds__(1024)
vsmax_k(const bf16_t* __restrict__ lg, float* __restrict__ out) {
  __shared__ float rm[16], rs[16];
  const int row = blockIdx.x, t = threadIdx.x;
  const bf16_t* lr = lg + (long)row * NVOCAB;
  float* r = out + (long)row * NVOCAB;
  float v[32];
  float m = -1e30f;
  #pragma unroll
  for (int j = 0; j < 16; ++j) {
    const int c = 2 * (j * 1024 + t);
    if (j < 15 || t < 640) {                 // c < 32000
      PackU u; u.u = *(const u32*)(lr + c);
      v[2 * j]     = (float)u.h[0];
      v[2 * j + 1] = (float)u.h[1];
      m = fmaxf(m, fmaxf(v[2 * j], v[2 * j + 1]));
    } else {
      v[2 * j] = v[2 * j + 1] = -1e30f;
    }
  }
  float s = 0.0f;
  #pragma unroll
  for (int j = 0; j < 32; ++j) s += expf(v[j] - m);
  #pragma unroll
  for (int o = 32; o > 0; o >>= 1) {
    const float mo = __shfl_down(m, o, 64);
    const float so = __shfl_down(s, o, 64);
    const float M2 = fmaxf(m, mo);
    s = s * expf(m - M2) + so * expf(mo - M2);
    m = M2;
  }
  if ((t & 63) == 0) { rm[t >> 6] = m; rs[t >> 6] = s; }
  __syncthreads();
  float M = -1e30f;
  #pragma unroll
  for (int i = 0; i < 16; ++i) M = fmaxf(M, rm[i]);
  float S = 0.0f;
  #pragma unroll
  for (int i = 0; i < 16; ++i) S += rs[i] * expf(rm[i] - M);
  const float inv = 1.0f / S;
  #pragma unroll
  for (int j = 0; j < 16; ++j) {
    const int c = 2 * (j * 1024 + t);
    if (j < 15 || t < 640) {
      float2 p; p.x = expf(v[2 * j] - M) * inv; p.y = expf(v[2 * j + 1] - M) * inv;
      *(float2*)(r + c) = p;
    }
  }
}

// ---------------------------------------------------------------- launch
extern "C" void kernel_launch(void* const* d_in, const int* in_sizes, int n_in,
                              void* d_out, int out_size, void* d_ws, size_t ws_size,
                              hipStream_t stream) {
  (void)in_sizes; (void)n_in; (void)out_size; (void)ws_size;
  const int*   x_ids = (const int*)  d_in[0];
  const float* wemb  = (const float*)d_in[1];
  const float* pemb  = (const float*)d_in[2];
  const float* Wq    = (const float*)d_in[3];
  const float* bq    = (const float*)d_in[4];
  const float* Wk    = (const float*)d_in[5];
  const float* bk    = (const float*)d_in[6];
  const float* Wv    = (const float*)d_in[7];
  const float* bv    = (const float*)d_in[8];
  const float* Wo    = (const float*)d_in[9];
  const float* bo    = (const float*)d_in[10];
  const float* g1    = (const float*)d_in[11];
  const float* b1    = (const float*)d_in[12];
  const float* g2    = (const float*)d_in[13];
  const float* b2    = (const float*)d_in[14];
  const float* W1    = (const float*)d_in[15];
  const float* bm1   = (const float*)d_in[16];
  const float* W2    = (const float*)d_in[17];
  const float* bm2   = (const float*)d_in[18];
  const float* gf    = (const float*)d_in[19];
  const float* bfin  = (const float*)d_in[20];
  const float* Wu    = (const float*)d_in[21];
  const float* bu    = (const float*)d_in[22];

  char* ws = (char*)d_ws;
  float*  X    = (float*) ws;                           //   0- 4  fp32 residual
  bf16_t* ACT  = (bf16_t*)(ws + (4u   << 20));          //   4- 6
  bf16_t* VbT  = (bf16_t*)(ws + (6u   << 20));          //   6- 8  [h*64+v][seq]
  bf16_t* Yb   = (bf16_t*)(ws + (10u  << 20));          //  10-10.25 [q][128]
  bf16_t* H1   = (bf16_t*)(ws + (12u  << 20));          //  12-20
  bf16_t* QKb  = (bf16_t*)(ws + (20u  << 20));          //  20-84 [z=32][q][e]
  float*  PART = (float*) (ws + (84u  << 20));          //  84-100 MLP2 split-K
  float*  BIAS = (float*) (ws + (100u << 20));          // 100-100.5 [l*32+i][e]
  bf16_t* WTqk = (bf16_t*)(ws + (128u << 20));          // 128-384 [l*32+i][e][d]
  bf16_t* LOGIT= (bf16_t*)(ws + (128u << 20));          // 128-190.5 (WTqk[0] dead by unembed)
  bf16_t* WTv  = (bf16_t*)(ws + (384u << 20));          // 384-392 [l*16+h][v][d]
  bf16_t* WTo  = (bf16_t*)(ws + (392u << 20));          // 392-393 [l][e][128]
  bf16_t* WT1  = (bf16_t*)(ws + (400u << 20));          // 400-432 [l][dm][d]
  bf16_t* WT2  = (bf16_t*)(ws + (432u << 20));          // 432-464 [l][d][dm]
  bf16_t* WTu  = (bf16_t*)(ws + (464u << 20));          // 464-526.5 [v][d]

  bf16_t* Sb  = (bf16_t*)d_out;                         // 32 MiB raw scores
  float*  OUT = (float*)d_out;

  const long DD = (long)DEMB * DEMB;
  const long SD = (long)SEQ * DEMB;

  // ---------------- prologue (2 launches)
  embedlnbias_k<<<SEQ + 128 + 64, 256, 0, stream>>>(
      x_ids, wemb, pemb, g1, b1, X, ACT, bq, bk, BIAS, Yb);
  tconvall_k<<<25056, 256, 0, stream>>>(Wq, Wk, Wv, Wo, W1, W2, Wu,
                                        WTqk, WTv, WTo, WT1, WT2, WTu);

  for (int l = 0; l < NLAYER; ++l) {
    // Q|K projection: z = 32 heads (512 blocks = 2 clean block-waves)
    gemm256_k<0, false, -1, false><<<dim3(4, 4, 32), 512, 0, stream>>>(
        ACT, WTqk + (long)l * 32 * DD, BIAS + (long)l * 32 * DEMB, QKb,
        SEQ, DEMB, DEMB, 0L, DD, SD, DEMB,
        nullptr, nullptr, nullptr, nullptr);

    // scores (160 causal-active tiles) + V projection (16 tiles): 176 packed blocks
    gemm256_k<0, true, 0, true><<<dim3(176), 512, 0, stream>>>(
        QKb, QKb + (long)NHEAD * SD, nullptr, Sb,
        SEQ, SEQ, DEMB, SD, SD, (long)SEQ * SEQ, 0,
        ACT, WTv + (long)l * DD, bv + (long)l * NHEAD * DVDIM, VbT);

    // softmax (4 rows/block) + full AV -> Yb
    smax_k<<<dim3(SEQ / 4, NHEAD), 256, 0, stream>>>(Sb, VbT, Yb);

    // x += y @ Wo + bo (K=128), BN=64 -> 128 blocks
    gemm_k<1, 64, false, false><<<dim3(16, 8, 1), 256, 0, stream>>>(
        Yb, WTo + (long)l * DEMB * 128, bo + (long)l * DEMB, X,
        SEQ, DEMB, 128, 128, 128, 0L, 0L, 0L, 0);

    // LN2
    ln_k<<<SEQ, 256, 0, stream>>>(X, g2 + l * DEMB, b2 + l * DEMB, ACT, X);

    // MLP1: gelu(xn2 @ W1 + bm1)
    gemm_k<3, 128, false, false><<<dim3(32, 8, 1), 256, 0, stream>>>(
        ACT, WT1 + (long)l * DMLP * DEMB, bm1 + (long)l * DMLP, H1,
        SEQ, DMLP, DEMB, DEMB, DEMB, 0L, 0L, 0L, 0);
    // MLP2 split-K
    gemm_k<2, 128, false, false><<<dim3(8, 8, 4), 256, 0, stream>>>(
        H1, WT2 + (long)l * DEMB * DMLP, nullptr, PART,
        SEQ, DEMB, 1024, DMLP, DMLP, 1024L, 1024L, (long)SEQ * DEMB, 0);
    // reduce + X update + LN (next layer's LN1 or final LN)
    if (l < NLAYER - 1)
      redln_k<<<SEQ, 256, 0, stream>>>(PART, bm2 + (long)l * DEMB, X,
                                       g1 + (l + 1) * DEMB, b1 + (l + 1) * DEMB, ACT);
    else
      redln_k<<<SEQ, 256, 0, stream>>>(PART, bm2 + (long)l * DEMB, X, gf, bfin, ACT);
  }

  // unembed -> bf16 logits (into dead WTqk[0] space), then softmax -> fp32 probs
  gemm256_k<0, false, -1, false><<<dim3(125, 4, 1), 512, 0, stream>>>(
      ACT, WTu, bu, LOGIT, SEQ, NVOCAB, DEMB, 0L, 0L, 0L, 0,
      nullptr, nullptr, nullptr, nullptr);
  vsmax_k<<<SEQ, 1024, 0, stream>>>(LOGIT, OUT);
}

// Round 16
// 1366.925 us; speedup vs baseline: 1.0229x; 1.0005x over previous
//
#include <hip/hip_runtime.h>

typedef __bf16 bf16_t;
typedef __bf16 bf16x8 __attribute__((ext_vector_type(8)));
typedef float f32x4 __attribute__((ext_vector_type(4)));
typedef unsigned int u32;

#define SEQ    1024
#define DEMB   1024
#define NHEAD  16
#define DVDIM  64
#define DMLP   4096
#define NVOCAB 32000
#define NLAYER 4

typedef const __attribute__((address_space(1))) void gas_t;
typedef __attribute__((address_space(3))) void las_t;

__device__ __forceinline__ void gload_lds16(const void* g, void* l) {
  __builtin_amdgcn_global_load_lds((gas_t*)g, (las_t*)l, 16, 0, 0);
}

// bijective chunked XCD swizzle (m204): dispatch id -> tile id so that each
// XCD (id%8) owns a contiguous chunk of tiles.
__device__ __forceinline__ int xcd_swz(int id, int nb) {
  const int q = nb >> 3, r = nb & 7;
  const int x = id & 7, off = id >> 3;
  return (x < r) ? x * (q + 1) + off : r * (q + 1) + (x - r) * q + off;
}

union PackU { bf16_t h[2]; u32 u; };
union B4U  { uint2 u; bf16_t h[4]; };

// ---------------------------------------------------------------- reductions
__device__ __forceinline__ float blockSum(float v, float* red) {
  #pragma unroll
  for (int o = 32; o > 0; o >>= 1) v += __shfl_down(v, o, 64);
  __syncthreads();
  if ((threadIdx.x & 63) == 0) red[threadIdx.x >> 6] = v;
  __syncthreads();
  return (red[0] + red[1]) + (red[2] + red[3]);
}

// ---------------------------------------------------------------- LN body
__device__ __forceinline__ void ln_body(float4 v, const float* __restrict__ g,
                                        const float* __restrict__ b,
                                        bf16_t* __restrict__ xn, int row, int t,
                                        float* red, float* xupd_row) {
  float mu = blockSum(v.x + v.y + v.z + v.w, red) * (1.0f / DEMB);
  float dx = v.x - mu, dy = v.y - mu, dz = v.z - mu, dw = v.w - mu;
  float var = blockSum(dx * dx + dy * dy + dz * dz + dw * dw, red) * (1.0f / DEMB);
  float inv = 1.0f / sqrtf(var);
  float4 gv = *(const float4*)(g + t * 4);
  float4 bv = *(const float4*)(b + t * 4);
  float o0 = gv.x * dx * inv + bv.x;
  float o1 = gv.y * dy * inv + bv.y;
  float o2 = gv.z * dz * inv + bv.z;
  float o3 = gv.w * dw * inv + bv.w;
  PackU p0, p1;
  p0.h[0] = (bf16_t)o0; p0.h[1] = (bf16_t)o1;
  p1.h[0] = (bf16_t)o2; p1.h[1] = (bf16_t)o3;
  uint2 st; st.x = p0.u; st.y = p1.u;
  *(uint2*)(xn + (long)row * DEMB + t * 4) = st;
  if (xupd_row) {
    float4 nv; nv.x = v.x + o0; nv.y = v.y + o1; nv.z = v.z + o2; nv.w = v.w + o3;
    *(float4*)(xupd_row + t * 4) = nv;
  }
}

// ---------------------------------------------------------------- prologue combo: embed+LN1(l0) | bias concat | Yb zero
__global__ void __launch_bounds__(256)
embedlnbias_k(const int* __restrict__ ids, const float* __restrict__ we,
              const float* __restrict__ pe, const float* __restrict__ g,
              const float* __restrict__ b, float* __restrict__ x,
              bf16_t* __restrict__ xn,
              const float* __restrict__ bq, const float* __restrict__ bk,
              float* __restrict__ bias_out, bf16_t* __restrict__ y) {
  __shared__ float red[4];
  const int bidx = blockIdx.x, t = threadIdx.x;
  if (bidx < SEQ) {
    const int row = bidx;
    const long id = ids[row];
    float4 a = *(const float4*)(we + id * (long)DEMB + t * 4);
    float4 p = *(const float4*)(pe + (long)row * DEMB + t * 4);
    float4 v; v.x = a.x + p.x; v.y = a.y + p.y; v.z = a.z + p.z; v.w = a.w + p.w;
    *(float4*)(x + (long)row * DEMB + t * 4) = v;
    ln_body(v, g, b, xn, row, t, red, nullptr);
  } else if (bidx < SEQ + 128) {
    const int z = bidx - SEQ;
    const int l = z >> 5, i = z & 31;
    const float* src = (i < NHEAD) ? (bq + (long)(l * NHEAD + i) * DEMB)
                                   : (bk + (long)(l * NHEAD + i - NHEAD) * DEMB);
    *(float4*)(bias_out + (long)z * DEMB + t * 4) = *(const float4*)(src + t * 4);
  } else {
    const int z = bidx - SEQ - 128;
    *(uint4*)((char*)y + ((long)z * 256 + t) * 16) = uint4{0, 0, 0, 0};
  }
}

// ---------------------------------------------------------------- layernorm (mid-layer ln2)
__global__ void __launch_bounds__(256)
ln_k(const float* __restrict__ x, const float* __restrict__ g,
     const float* __restrict__ b, bf16_t* __restrict__ xn,
     float* __restrict__ xupd) {
  __shared__ float red[4];
  const int row = blockIdx.x, t = threadIdx.x;
  float4 v = *(const float4*)(x + (long)row * DEMB + t * 4);
  ln_body(v, g, b, xn, row, t, red, xupd ? xupd + (long)row * DEMB : nullptr);
}

// ---------------------------------------------------------------- MLP2 reduce + X update + LN(next/final)
__global__ void __launch_bounds__(256)
redln_k(const float* __restrict__ P, const float* __restrict__ bm2,
        float* __restrict__ X, const float* __restrict__ g,
        const float* __restrict__ b, bf16_t* __restrict__ xn) {
  __shared__ float red[4];
  const int row = blockIdx.x, t = threadIdx.x;
  const long i = (long)row * 1024 + t * 4;
  float4 x = *(float4*)(X + i);
  #pragma unroll
  for (int z = 0; z < 4; ++z) {
    float4 p = *(const float4*)(P + (long)z * 1048576 + i);
    x.x += p.x; x.y += p.y; x.z += p.z; x.w += p.w;
  }
  float4 bb = *(const float4*)(bm2 + t * 4);
  x.x += bb.x; x.y += bb.y; x.z += bb.z; x.w += bb.w;
  *(float4*)(X + i) = x;
  ln_body(x, g, b, xn, row, t, red, nullptr);
}

// ---------------------------------------------------------------- fused all-weights transpose-convert
// 128x64 tile: float4 loads -> fp32 [128][65] LDS -> plain uint4 bf16 stores.
__device__ __forceinline__ void tconv_tile(const float* __restrict__ ip,
                                           bf16_t* __restrict__ op,
                                           int R, int C, int rx, int ry,
                                           float (*tf)[65]) {
  const int c0 = rx * 64, r0 = ry * 128;
  const int t = threadIdx.x;
  #pragma unroll
  for (int p = 0; p < 8; ++p) {
    const int i = p * 256 + t;
    const int r = i >> 4, c4 = (i & 15) * 4;
    const float4 v = *(const float4*)(ip + (long)(r0 + r) * C + (c0 + c4));
    *(float4*)&tf[r][c4] = v;
  }
  __syncthreads();
  const int nn = t >> 2;
  const int sub = t & 3;
  #pragma unroll
  for (int q2 = 0; q2 < 4; ++q2) {
    const int base = q2 * 32 + sub * 8;
    u32 w[4];
    #pragma unroll
    for (int q = 0; q < 4; ++q) {
      PackU u;
      u.h[0] = (bf16_t)tf[base + 2 * q][nn];
      u.h[1] = (bf16_t)tf[base + 2 * q + 1][nn];
      w[q] = u.u;
    }
    *(uint4*)(op + (long)(c0 + nn) * R + (r0 + base)) = *(uint4*)&w[0];
  }
}

__global__ void __launch_bounds__(256)
tconvall_k(const float* __restrict__ Wq, const float* __restrict__ Wk,
           const float* __restrict__ Wv, const float* __restrict__ Wo,
           const float* __restrict__ W1, const float* __restrict__ W2,
           const float* __restrict__ Wu,
           bf16_t* __restrict__ WTqk, bf16_t* __restrict__ WTv,
           bf16_t* __restrict__ WTo, bf16_t* __restrict__ WT1,
           bf16_t* __restrict__ WT2, bf16_t* __restrict__ WTu) {
  __shared__ float tf[128][65];
  const long DD = (long)DEMB * DEMB;
  const int b = blockIdx.x;
  const float* ip; bf16_t* op; int R, C, rx, ry;
  if (b < 16384) {                       // Wq|Wk: 128 z x (8 ry x 16 rx)
    const int z = b >> 7, rem = b & 127; ry = rem >> 4; rx = rem & 15;
    R = 1024; C = 1024;
    const int l = z >> 5, i = z & 31;
    ip = (i < NHEAD) ? (Wq + (long)(l * NHEAD + i) * DD)
                     : (Wk + (long)(l * NHEAD + i - NHEAD) * DD);
    op = WTqk + (long)z * DD;
  } else if (b < 16896) {                // Wv: 64 z x (8 ry x 1 rx)
    const int idx = b - 16384; const int z = idx >> 3; ry = idx & 7; rx = 0;
    R = 1024; C = 64;
    ip = Wv + (long)z * 65536; op = WTv + (long)z * 65536;
  } else if (b < 16960) {                // Wo (rows 0..127): 4 z x (1 ry x 16 rx)
    const int idx = b - 16896; const int z = idx >> 4; ry = 0; rx = idx & 15;
    R = 128; C = 1024;
    ip = Wo + (long)z * DD; op = WTo + (long)z * 131072;
  } else if (b < 19008) {                // W1: 4 z x (8 ry x 64 rx)
    const int idx = b - 16960; const int z = idx >> 9, rem = idx & 511;
    ry = rem >> 6; rx = rem & 63;
    R = 1024; C = 4096;
    ip = W1 + (long)z * 4194304; op = WT1 + (long)z * 4194304;
  } else if (b < 21056) {                // W2: 4 z x (32 ry x 16 rx)
    const int idx = b - 19008; const int z = idx >> 9, rem = idx & 511;
    ry = rem >> 4; rx = rem & 15;
    R = 4096; C = 1024;
    ip = W2 + (long)z * 4194304; op = WT2 + (long)z * 4194304;
  } else {                               // Wu: 8 ry x 500 rx
    const int idx = b - 21056; ry = idx / 500; rx = idx - ry * 500;
    R = 1024; C = 32000;
    ip = Wu; op = WTu;
  }
  tconv_tile(ip, op, R, C, rx, ry, tf);
}

// ---------------------------------------------------------------- 128x128 GEMM (m97 structure)
// MODE: 1 fp32 +=, 2 fp32, 3 gelu->bf16.  (my-stride of these grids is a
// multiple of 8 -> m-tiles sharing a B-panel already land on one XCD.)
template<int MODE, int BN, bool CAUSAL, bool TRIMK>
__global__ void __launch_bounds__(256)
gemm_k(const bf16_t* __restrict__ A, const bf16_t* __restrict__ B,
       const float* __restrict__ bias, void* __restrict__ Cv,
       int M, int N, int K, int lda, int ldb,
       long aB, long bB, long cB, int biasB) {
  __shared__ bf16_t lsA[128 * 32];
  __shared__ bf16_t lsB[BN * 32];

  const int t = threadIdx.x;
  const int bz = blockIdx.z;
  const int m0 = blockIdx.y * 128;
  const int n0 = blockIdx.x * BN;
  if (CAUSAL && n0 > m0 + 127) return;

  const bf16_t* Ap = A + (long)bz * aB;
  const bf16_t* Bp = B + (long)bz * bB;
  const int kEnd = TRIMK ? min(K, m0 + 128) : K;

  constexpr int NS = BN / 32;
  const int lane = t & 63;
  const int wid = t >> 6;
  const int wr = (wid >> 1) * 64;
  const int wc = (wid & 1) * (BN / 2);
  const int fr = lane & 15, fg = lane >> 4;
  const int srow = lane >> 2;
  const int skc  = (lane & 3) * 8;

  f32x4 acc[4][NS] = {};

  for (int k0 = 0; k0 < kEnd; k0 += 32) {
    if (k0) __syncthreads();
    #pragma unroll
    for (int i = 0; i < 2; ++i) {
      const int seg = wid * 2 + i;
      gload_lds16(Ap + (long)(m0 + seg * 16 + srow) * lda + (k0 + skc),
                  lsA + seg * 512);
    }
    if (BN == 128) {
      #pragma unroll
      for (int i = 0; i < 2; ++i) {
        const int seg = wid * 2 + i;
        gload_lds16(Bp + (long)(n0 + seg * 16 + srow) * ldb + (k0 + skc),
                    lsB + seg * 512);
      }
    } else {
      gload_lds16(Bp + (long)(n0 + wid * 16 + srow) * ldb + (k0 + skc),
                  lsB + wid * 512);
    }
    __syncthreads();

    bf16x8 af[4], bfv[NS];
    #pragma unroll
    for (int ms = 0; ms < 4; ++ms)
      af[ms] = *(const bf16x8*)(lsA + (wr + ms * 16 + fr) * 32 + fg * 8);
    #pragma unroll
    for (int ns = 0; ns < NS; ++ns)
      bfv[ns] = *(const bf16x8*)(lsB + (wc + ns * 16 + fr) * 32 + fg * 8);
    #pragma unroll
    for (int ms = 0; ms < 4; ++ms)
      #pragma unroll
      for (int ns = 0; ns < NS; ++ns)
        acc[ms][ns] = __builtin_amdgcn_mfma_f32_16x16x32_bf16(
            af[ms], bfv[ns], acc[ms][ns], 0, 0, 0);
  }

  #pragma unroll
  for (int ms = 0; ms < 4; ++ms) {
    #pragma unroll
    for (int ns = 0; ns < NS; ++ns) {
      const int col = n0 + wc + ns * 16 + fr;
      const float bvv = bias ? bias[(long)bz * biasB + col] : 0.0f;
      #pragma unroll
      for (int r = 0; r < 4; ++r) {
        const int row = m0 + wr + ms * 16 + fg * 4 + r;
        float v = acc[ms][ns][r] + bvv;
        if (MODE == 1) {
          ((float*)Cv)[(long)bz * cB + (long)row * N + col] += v;
        } else if (MODE == 2) {
          ((float*)Cv)[(long)bz * cB + (long)row * N + col] = v;
        } else {
          float gl = 0.5f * v * (1.0f + tanhf(0.7978845608028654f * (v + 0.044715f * v * v * v)));
          ((bf16_t*)Cv)[(long)bz * cB + (long)row * N + col] = (bf16_t)gl;
        }
      }
    }
  }
}

// ---------------------------------------------------------------- 256x256 8-phase GEMM (m201 template)
#define GPHASE(buf, mh, nh, STAGE, VM) do {                                            \
  bf16x8 af[4][2], bfv[2][2];                                                          \
  _Pragma("unroll") for (int mf = 0; mf < 4; ++mf) {                                   \
    const int r = wm * 128 + ((mh) * 4 + mf) * 16 + (lane & 15);                       \
    _Pragma("unroll") for (int ks = 0; ks < 2; ++ks) {                                 \
      const int slot = ks * 4 + (lane >> 4);                                           \
      af[mf][ks] = *(const bf16x8*)(lds + (buf) * 32768 + r * 64 +                     \
                                    ((slot ^ (r & 7)) << 3)); } }                      \
  _Pragma("unroll") for (int nf = 0; nf < 2; ++nf) {                                   \
    const int r = wn * 64 + ((nh) * 2 + nf) * 16 + (lane & 15);                        \
    _Pragma("unroll") for (int ks = 0; ks < 2; ++ks) {                                 \
      const int slot = ks * 4 + (lane >> 4);                                           \
      bfv[nf][ks] = *(const bf16x8*)(lds + (buf) * 32768 + 16384 + r * 64 +            \
                                     ((slot ^ (r & 7)) << 3)); } }                     \
  STAGE;                                                                               \
  __builtin_amdgcn_s_barrier();                                                        \
  asm volatile("s_waitcnt lgkmcnt(0)" ::: "memory");                                   \
  __builtin_amdgcn_sched_barrier(0);                                                   \
  __builtin_amdgcn_s_setprio(1);                                                       \
  _Pragma("unroll") for (int mf = 0; mf < 4; ++mf)                                     \
    _Pragma("unroll") for (int nf = 0; nf < 2; ++nf)                                   \
      _Pragma("unroll") for (int ks = 0; ks < 2; ++ks)                                 \
        acc[(mh) * 4 + mf][(nh) * 2 + nf] = __builtin_amdgcn_mfma_f32_16x16x32_bf16(   \
            af[mf][ks], bfv[nf][ks], acc[(mh) * 4 + mf][(nh) * 2 + nf], 0, 0, 0);      \
  __builtin_amdgcn_s_setprio(0);                                                       \
  VM;                                                                                  \
  __builtin_amdgcn_s_barrier();                                                        \
} while (0)

// GEO 0: QK projection, 512 tiles my-major ((z*4+bx)*4+my), XCD-chunked.
// GEO 1: scores (160, head-major h*10+pi triangular) + V rider (tiles 160..175).
// GEO 2: unembed, 500 tiles n-major (n*4+m), XCD-chunked (bijective, 500%8!=0).
template<int MODE, int GEO>
__global__ void __launch_bounds__(512, 1)
gemm256_k(const bf16_t* __restrict__ A, const bf16_t* __restrict__ B,
          const float* __restrict__ bias, void* __restrict__ Cv,
          int M, int N, int K, long aB, long bB, long cB, int biasB,
          const bf16_t* __restrict__ A2, const bf16_t* __restrict__ B2,
          const float* __restrict__ bias2, bf16_t* __restrict__ Cv2) {
  __shared__ bf16_t lds[65536];

  const int t = threadIdx.x;
  const int lane = t & 63, w = t >> 6;
  const int wm = w >> 2, wn = w & 3;
  int m0, n0, zz; bool vm = false;
  if (GEO == 0) {
    const int tile = xcd_swz(blockIdx.x, 512);
    m0 = (tile & 3) * 256; n0 = ((tile >> 2) & 3) * 256; zz = tile >> 4;
  } else if (GEO == 1) {
    const int tile = xcd_swz(blockIdx.x, 176);
    if (tile >= 160) {
      vm = true; zz = 0;
      const int rem = tile - 160;
      m0 = (rem >> 2) * 256; n0 = (rem & 3) * 256;
    } else {
      zz = tile / 10;
      const int pi = tile - zz * 10;
      const int by = (pi >= 1) + (pi >= 3) + (pi >= 6);
      const int bx = pi - (by * (by + 1)) / 2;
      m0 = by * 256; n0 = bx * 256;
    }
  } else {
    const int tile = xcd_swz(blockIdx.x, 500);
    n0 = (tile >> 2) * 256; m0 = (tile & 3) * 256; zz = 0;
  }

  const bf16_t* Ap = vm ? A2 : A + (long)zz * aB;
  const bf16_t* Bp = vm ? B2 : B + (long)zz * bB;
  const int NT = K >> 6;

  f32x4 acc[8][4] = {};

  auto stA = [&](int half, int kt, int buf) {
    #pragma unroll
    for (int rr = 0; rr < 2; ++rr) {
      const int rw0 = rr * 64 + w * 8;
      const int row0 = ((rw0 >> 6) << 7) | (half << 6) | (rw0 & 63);
      const int r = row0 + (lane >> 3);
      const int slot = lane & 7;
      gload_lds16(Ap + (long)(m0 + r) * K + (kt << 6) + ((slot ^ (r & 7)) << 3),
                  lds + buf * 32768 + row0 * 64);
    }
  };
  auto stB = [&](int half, int kt, int buf) {
    #pragma unroll
    for (int rr = 0; rr < 2; ++rr) {
      const int rw0 = rr * 64 + w * 8;
      const int row0 = ((rw0 >> 5) << 6) | (half << 5) | (rw0 & 31);
      const int r = row0 + (lane >> 3);
      const int slot = lane & 7;
      gload_lds16(Bp + (long)(n0 + r) * K + (kt << 6) + ((slot ^ (r & 7)) << 3),
                  lds + buf * 32768 + 16384 + row0 * 64);
    }
  };

  stB(0, 0, 0); stA(0, 0, 0); stA(1, 0, 0); stB(1, 0, 0);
  stB(0, 1, 1); stA(0, 1, 1);
  asm volatile("s_waitcnt vmcnt(4)" ::: "memory");
  __builtin_amdgcn_s_barrier();

  for (int it = 0; it < (NT >> 1); ++it) {
    const int tt = it * 2;
    const int s1 = min(tt + 1, NT - 1);
    const int s2 = min(tt + 2, NT - 1);
    const int s3 = min(tt + 3, NT - 1);
    GPHASE(0, 0, 0, { stA(1, s1, 1); }, );
    GPHASE(0, 1, 0, { stB(1, s1, 1); }, );
    GPHASE(0, 0, 1, { stB(0, s2, 0); }, );
    GPHASE(0, 1, 1, { stA(0, s2, 0); }, asm volatile("s_waitcnt vmcnt(4)" ::: "memory"));
    GPHASE(1, 0, 0, { stA(1, s2, 0); }, );
    GPHASE(1, 1, 0, { stB(1, s2, 0); }, );
    GPHASE(1, 0, 1, { stB(0, s3, 1); }, );
    GPHASE(1, 1, 1, { stA(0, s3, 1); }, asm volatile("s_waitcnt vmcnt(4)" ::: "memory"));
  }
  asm volatile("s_waitcnt vmcnt(0)" ::: "memory");

  #pragma unroll
  for (int mf = 0; mf < 8; ++mf) {
    #pragma unroll
    for (int nf = 0; nf < 4; ++nf) {
      const int col = n0 + wn * 64 + nf * 16 + (lane & 15);
      const int row0 = m0 + wm * 128 + mf * 16 + (lane >> 4) * 4;
      if (vm) {
        const float bvv = bias2[col];
        PackU p0, p1;
        p0.h[0] = (bf16_t)(acc[mf][nf][0] + bvv);
        p0.h[1] = (bf16_t)(acc[mf][nf][1] + bvv);
        p1.h[0] = (bf16_t)(acc[mf][nf][2] + bvv);
        p1.h[1] = (bf16_t)(acc[mf][nf][3] + bvv);
        uint2 st; st.x = p0.u; st.y = p1.u;
        *(uint2*)(Cv2 + (long)col * M + row0) = st;
      } else {
        const float bvv = bias ? bias[(long)zz * biasB + col] : 0.0f;
        #pragma unroll
        for (int r = 0; r < 4; ++r) {
          const float v = acc[mf][nf][r] + bvv;
          if (MODE == 0)
            ((bf16_t*)Cv)[(long)zz * cB + (long)(row0 + r) * N + col] = (bf16_t)v;
          else
            ((float*)Cv)[(long)zz * cB + (long)(row0 + r) * N + col] = v;
        }
      }
    }
  }
}

// ---------------------------------------------------------------- softmax: 4 rows/block, wave-per-row butterfly
__global__ void __launch_bounds__(256)
smax_k(const bf16_t* __restrict__ s, const bf16_t* __restrict__ V,
       bf16_t* __restrict__ Yb) {
  __shared__ float pl[4][1024];
  const int qb = blockIdx.x, h = blockIdx.y, t = threadIdx.x;
  const int w = t >> 6, lane = t & 63;
  const int q = qb * 4 + w;
  const bf16_t* sr = s + ((long)h * SEQ + q) * SEQ;
  const int L = q + 1;
  const float scale = 0.03125f;
  float e[16];
  float m = -1e30f;
  #pragma unroll
  for (int c = 0; c < 4; ++c) {
    B4U bb; bb.u = *(const uint2*)(sr + lane * 16 + c * 4);
    #pragma unroll
    for (int j = 0; j < 4; ++j) {
      const float x = (float)bb.h[j] * scale;
      e[c * 4 + j] = x;
      if (lane * 16 + c * 4 + j < L) m = fmaxf(m, x);
    }
  }
  #pragma unroll
  for (int o = 32; o > 0; o >>= 1) m = fmaxf(m, __shfl_xor(m, o, 64));
  float sum = 0.0f;
  #pragma unroll
  for (int i = 0; i < 16; ++i) {
    e[i] = (lane * 16 + i < L) ? expf(e[i] - m) : 0.0f;
    sum += e[i];
  }
  #pragma unroll
  for (int o = 32; o > 0; o >>= 1) sum += __shfl_xor(sum, o, 64);
  const float inv = 1.0f / sum;

  if (h != NHEAD - 1) {
    const bf16_t* vc = V + (long)h * 64 * SEQ + lane * 16;
    float d = 0.0f;
    #pragma unroll
    for (int c = 0; c < 4; ++c) {
      B4U vv; vv.u = *(const uint2*)(vc + c * 4);
      #pragma unroll
      for (int j = 0; j < 4; ++j) d += e[c * 4 + j] * (float)vv.h[j];
    }
    #pragma unroll
    for (int o = 32; o > 0; o >>= 1) d += __shfl_xor(d, o, 64);
    if (lane == 0) Yb[(long)q * 128 + h] = (bf16_t)(d * inv);
  } else {
    #pragma unroll
    for (int c = 0; c < 4; ++c)
      *(float4*)&pl[w][lane * 16 + c * 4] = *(float4*)&e[c * 4];
    __syncthreads();
    const int c = t & 63, r = t >> 6;
    const int qq = qb * 4 + r;
    const bf16_t* vr = V + ((long)(NHEAD - 1) * 64 + c) * SEQ;
    float d = 0.0f;
    for (int kk = 0; kk < 1024; kk += 8) {
      bf16x8 v8 = *(const bf16x8*)(vr + kk);
      #pragma unroll
      for (int j = 0; j < 8; ++j) d += pl[r][kk + j] * (float)v8[j];
    }
    float sr2 = 0.0f;
    for (int kk = t & 63; kk < 1024; kk += 64) sr2 += pl[r][kk];
    #pragma unroll
    for (int o = 32; o > 0; o >>= 1) sr2 += __shfl_xor(sr2, o, 64);
    Yb[(long)qq * 128 + 15 + c] = (bf16_t)(d / sr2);
  }
}

// ---------------------------------------------------------------- final vocab softmax: bf16 logits -> fp32 probs
__global__ void __launch_bounds__(1024)
vsmax_k(const bf16_t* __restrict__ lg, float* __restrict__ out) {
  __shared__ float rm[16], rs[16];
  const int row = blockIdx.x, t = threadIdx.x;
  const bf16_t* lr = lg + (long)row * NVOCAB;
  float* r = out + (long)row * NVOCAB;
  float v[32];
  float m = -1e30f;
  #pragma unroll
  for (int j = 0; j < 16; ++j) {
    const int c = 2 * (j * 1024 + t);
    if (j < 15 || t < 640) {
      PackU u; u.u = *(const u32*)(lr + c);
      v[2 * j]     = (float)u.h[0];
      v[2 * j + 1] = (float)u.h[1];
      m = fmaxf(m, fmaxf(v[2 * j], v[2 * j + 1]));
    } else {
      v[2 * j] = v[2 * j + 1] = -1e30f;
    }
  }
  float s = 0.0f;
  #pragma unroll
  for (int j = 0; j < 32; ++j) s += expf(v[j] - m);
  #pragma unroll
  for (int o = 32; o > 0; o >>= 1) {
    const float mo = __shfl_down(m, o, 64);
    const float so = __shfl_down(s, o, 64);
    const float M2 = fmaxf(m, mo);
    s = s * expf(m - M2) + so * expf(mo - M2);
    m = M2;
  }
  if ((t & 63) == 0) { rm[t >> 6] = m; rs[t >> 6] = s; }
  __syncthreads();
  float M = -1e30f;
  #pragma unroll
  for (int i = 0; i < 16; ++i) M = fmaxf(M, rm[i]);
  float S = 0.0f;
  #pragma unroll
  for (int i = 0; i < 16; ++i) S += rs[i] * expf(rm[i] - M);
  const float inv = 1.0f / S;
  #pragma unroll
  for (int j = 0; j < 16; ++j) {
    const int c = 2 * (j * 1024 + t);
    if (j < 15 || t < 640) {
      float2 p; p.x = expf(v[2 * j] - M) * inv; p.y = expf(v[2 * j + 1] - M) * inv;
      *(float2*)(r + c) = p;
    }
  }
}

// ---------------------------------------------------------------- launch
extern "C" void kernel_launch(void* const* d_in, const int* in_sizes, int n_in,
                              void* d_out, int out_size, void* d_ws, size_t ws_size,
                              hipStream_t stream) {
  (void)in_sizes; (void)n_in; (void)out_size; (void)ws_size;
  const int*   x_ids = (const int*)  d_in[0];
  const float* wemb  = (const float*)d_in[1];
  const float* pemb  = (const float*)d_in[2];
  const float* Wq    = (const float*)d_in[3];
  const float* bq    = (const float*)d_in[4];
  const float* Wk    = (const float*)d_in[5];
  const float* bk    = (const float*)d_in[6];
  const float* Wv    = (const float*)d_in[7];
  const float* bv    = (const float*)d_in[8];
  const float* Wo    = (const float*)d_in[9];
  const float* bo    = (const float*)d_in[10];
  const float* g1    = (const float*)d_in[11];
  const float* b1    = (const float*)d_in[12];
  const float* g2    = (const float*)d_in[13];
  const float* b2    = (const float*)d_in[14];
  const float* W1    = (const float*)d_in[15];
  const float* bm1   = (const float*)d_in[16];
  const float* W2    = (const float*)d_in[17];
  const float* bm2   = (const float*)d_in[18];
  const float* gf    = (const float*)d_in[19];
  const float* bfin  = (const float*)d_in[20];
  const float* Wu    = (const float*)d_in[21];
  const float* bu    = (const float*)d_in[22];

  char* ws = (char*)d_ws;
  float*  X    = (float*) ws;                           //   0- 4  fp32 residual
  bf16_t* ACT  = (bf16_t*)(ws + (4u   << 20));          //   4- 6
  bf16_t* VbT  = (bf16_t*)(ws + (6u   << 20));          //   6- 8  [h*64+v][seq]
  bf16_t* Yb   = (bf16_t*)(ws + (10u  << 20));          //  10-10.25 [q][128]
  bf16_t* H1   = (bf16_t*)(ws + (12u  << 20));          //  12-20
  bf16_t* QKb  = (bf16_t*)(ws + (20u  << 20));          //  20-84 [z=32][q][e]
  float*  PART = (float*) (ws + (84u  << 20));          //  84-100 MLP2 split-K
  float*  BIAS = (float*) (ws + (100u << 20));          // 100-100.5 [l*32+i][e]
  bf16_t* WTqk = (bf16_t*)(ws + (128u << 20));          // 128-384 [l*32+i][e][d]
  bf16_t* LOGIT= (bf16_t*)(ws + (128u << 20));          // 128-190.5 (WTqk[0] dead by unembed)
  bf16_t* WTv  = (bf16_t*)(ws + (384u << 20));          // 384-392 [l*16+h][v][d]
  bf16_t* WTo  = (bf16_t*)(ws + (392u << 20));          // 392-393 [l][e][128]
  bf16_t* WT1  = (bf16_t*)(ws + (400u << 20));          // 400-432 [l][dm][d]
  bf16_t* WT2  = (bf16_t*)(ws + (432u << 20));          // 432-464 [l][d][dm]
  bf16_t* WTu  = (bf16_t*)(ws + (464u << 20));          // 464-526.5 [v][d]

  bf16_t* Sb  = (bf16_t*)d_out;                         // 32 MiB raw scores
  float*  OUT = (float*)d_out;

  const long DD = (long)DEMB * DEMB;
  const long SD = (long)SEQ * DEMB;

  // ---------------- prologue (2 launches)
  embedlnbias_k<<<SEQ + 128 + 64, 256, 0, stream>>>(
      x_ids, wemb, pemb, g1, b1, X, ACT, bq, bk, BIAS, Yb);
  tconvall_k<<<25056, 256, 0, stream>>>(Wq, Wk, Wv, Wo, W1, W2, Wu,
                                        WTqk, WTv, WTo, WT1, WT2, WTu);

  for (int l = 0; l < NLAYER; ++l) {
    // Q|K projection: 512 tiles, my-major + XCD chunk (B-panel L2 locality)
    gemm256_k<0, 0><<<512, 512, 0, stream>>>(
        ACT, WTqk + (long)l * 32 * DD, BIAS + (long)l * 32 * DEMB, QKb,
        SEQ, DEMB, DEMB, 0L, DD, SD, DEMB,
        nullptr, nullptr, nullptr, nullptr);

    // scores (160 head-major causal tiles) + V rider (16): 176 packed + swizzle
    gemm256_k<0, 1><<<176, 512, 0, stream>>>(
        QKb, QKb + (long)NHEAD * SD, nullptr, Sb,
        SEQ, SEQ, DEMB, SD, SD, (long)SEQ * SEQ, 0,
        ACT, WTv + (long)l * DD, bv + (long)l * NHEAD * DVDIM, VbT);

    // softmax (4 rows/block) + full AV -> Yb
    smax_k<<<dim3(SEQ / 4, NHEAD), 256, 0, stream>>>(Sb, VbT, Yb);

    // x += y @ Wo + bo (K=128), BN=64 -> 128 blocks
    gemm_k<1, 64, false, false><<<dim3(16, 8, 1), 256, 0, stream>>>(
        Yb, WTo + (long)l * DEMB * 128, bo + (long)l * DEMB, X,
        SEQ, DEMB, 128, 128, 128, 0L, 0L, 0L, 0);

    // LN2
    ln_k<<<SEQ, 256, 0, stream>>>(X, g2 + l * DEMB, b2 + l * DEMB, ACT, X);

    // MLP1: gelu(xn2 @ W1 + bm1)
    gemm_k<3, 128, false, false><<<dim3(32, 8, 1), 256, 0, stream>>>(
        ACT, WT1 + (long)l * DMLP * DEMB, bm1 + (long)l * DMLP, H1,
        SEQ, DMLP, DEMB, DEMB, DEMB, 0L, 0L, 0L, 0);
    // MLP2 split-K
    gemm_k<2, 128, false, false><<<dim3(8, 8, 4), 256, 0, stream>>>(
        H1, WT2 + (long)l * DEMB * DMLP, nullptr, PART,
        SEQ, DEMB, 1024, DMLP, DMLP, 1024L, 1024L, (long)SEQ * DEMB, 0);
    // reduce + X update + LN (next layer's LN1 or final LN)
    if (l < NLAYER - 1)
      redln_k<<<SEQ, 256, 0, stream>>>(PART, bm2 + (long)l * DEMB, X,
                                       g1 + (l + 1) * DEMB, b1 + (l + 1) * DEMB, ACT);
    else
      redln_k<<<SEQ, 256, 0, stream>>>(PART, bm2 + (long)l * DEMB, X, gf, bfin, ACT);
  }

  // unembed -> bf16 logits (n-major swizzled), then softmax -> fp32 probs
  gemm256_k<0, 2><<<500, 512, 0, stream>>>(
      ACT, WTu, bu, LOGIT, SEQ, NVOCAB, DEMB, 0L, 0L, 0L, 0,
      nullptr, nullptr, nullptr, nullptr);
  vsmax_k<<<SEQ, 1024, 0, stream>>>(LOGIT, OUT);
}